// Round 12
// baseline (3081.761 us; speedup 1.0000x reference)
//
#include <hip/hip_runtime.h>
#include <hip/hip_bf16.h>
#include <math.h>

__device__ __forceinline__ float silu_f(float x) { return x / (1.0f + expf(-x)); }

// ---------------------------------------------------------------- CSR build
__global__ __launch_bounds__(256) void k_count(const int* __restrict__ ei, int* __restrict__ cnt,
                                               int nE) {
    int e = blockIdx.x * 256 + threadIdx.x;
    if (e < nE) atomicAdd(&cnt[ei[nE + e]], 1);
}

__global__ __launch_bounds__(1024) void k_scan_blk(const int* __restrict__ cnt,
                                                   int* __restrict__ offs,
                                                   int* __restrict__ btot, int N) {
    __shared__ int tmp[1024];
    const int tid = threadIdx.x;
    int i = blockIdx.x * 1024 + tid;
    int val = (i < N) ? cnt[i] : 0;
    tmp[tid] = val;
    __syncthreads();
    for (int off = 1; off < 1024; off <<= 1) {
        int t = (tid >= off) ? tmp[tid - off] : 0;
        __syncthreads();
        tmp[tid] += t;
        __syncthreads();
    }
    if (i < N) offs[i] = tmp[tid] - val;
    if (tid == 1023) btot[blockIdx.x] = tmp[1023];
}

__global__ void k_scan_top(const int* __restrict__ btot, int* __restrict__ btot2,
                           int nb, int* __restrict__ offsN) {
    int tid = threadIdx.x;
    int v = (tid < nb) ? btot[tid] : 0;
    int orig = v;
    #pragma unroll
    for (int off = 1; off < 64; off <<= 1) {
        int u = __shfl_up(v, off, 64);
        if (tid >= off) v += u;
    }
    btot2[tid] = v - orig;
    if (tid == 63) *offsN = v;
}

__global__ __launch_bounds__(256) void k_scan_add(int* __restrict__ offs,
                                                  const int* __restrict__ btot2, int N) {
    int i = blockIdx.x * 256 + threadIdx.x;
    if (i < N) offs[i] += btot2[i >> 10];
}

__global__ __launch_bounds__(256) void k_fill(const int* __restrict__ ei,
                                              const int* __restrict__ offs,
                                              int* __restrict__ cur, int* __restrict__ perm,
                                              int nE) {
    int e = blockIdx.x * 256 + threadIdx.x;
    if (e < nE) {
        int d = ei[nE + e];
        int p = atomicAdd(&cur[d], 1);
        perm[offs[d] + p] = e;
    }
}

// ---------------------------------------------------------------- per-edge trig precompute
__global__ __launch_bounds__(256) void k_prep(const float* __restrict__ edist,
                                              int* __restrict__ perm,
                                              float2* __restrict__ curc2,
                                              int nE, int nEpad) {
    int i = blockIdx.x * 256 + threadIdx.x;
    if (i >= nEpad) return;
    if (i >= nE) { perm[i] = 0; curc2[i] = make_float2(0.f, 0.f); return; }
    int e = perm[i];
    float dd = edist[e];
    float t = 0.62831853071795864769f * dd;  // pi*d/5
    float cs = cosf(t), sn = sinf(t);
    float cosc = (dd <= 5.0f) ? (0.5f * (cs + 1.0f)) : 0.0f;
    float ic = cosc / dd;
    curc2[i] = make_float2(sn * ic, 2.0f * cs);
}

// ---------------------------------------------------------------- fused init + layer-0 mf
__global__ __launch_bounds__(256, 4) void k_initmf(const int* __restrict__ z,
                                                   const float* __restrict__ emb,
                                                   float* __restrict__ s,
                                                   const float* __restrict__ W1,
                                                   const float* __restrict__ b1,
                                                   const float* __restrict__ W2,
                                                   const float* __restrict__ b2,
                                                   float* __restrict__ mf) {
    __shared__ float s_t[16 * 128];
    __shared__ float h_t[16 * 128];
    const int tid = threadIdx.x;
    const size_t nb = (size_t)blockIdx.x * 16;
    {
        float4* sg = (float4*)(s + nb * 128);
        #pragma unroll
        for (int r = 0; r < 2; ++r) {
            int j = tid + 256 * r;
            int node = j >> 5, c4 = j & 31;
            float4 val = ((const float4*)emb)[(size_t)z[nb + node] * 32 + c4];
            ((float4*)s_t)[j] = val;
            sg[j] = val;
        }
    }
    __syncthreads();
    const int c = tid & 127;
    const int g = tid >> 7;
    {
        float acc[8];
        float bb = b1[c];
        #pragma unroll
        for (int i = 0; i < 8; i++) acc[i] = bb;
        for (int k = 0; k < 128; k += 4) {
            float4 sv[8];
            #pragma unroll
            for (int i = 0; i < 8; i++) sv[i] = *(const float4*)&s_t[(g * 8 + i) * 128 + k];
            #pragma unroll
            for (int kk = 0; kk < 4; kk++) {
                float w = W1[(size_t)(k + kk) * 128 + c];
                #pragma unroll
                for (int i = 0; i < 8; i++) acc[i] = fmaf((&sv[i].x)[kk], w, acc[i]);
            }
        }
        #pragma unroll
        for (int i = 0; i < 8; i++) h_t[(g * 8 + i) * 128 + c] = silu_f(acc[i]);
    }
    __syncthreads();
    {
        float acc[8][3];
        #pragma unroll
        for (int q = 0; q < 3; q++) {
            float bb = b2[c + 128 * q];
            #pragma unroll
            for (int i = 0; i < 8; i++) acc[i][q] = bb;
        }
        for (int k = 0; k < 128; k += 4) {
            float4 hv[8];
            #pragma unroll
            for (int i = 0; i < 8; i++) hv[i] = *(const float4*)&h_t[(g * 8 + i) * 128 + k];
            #pragma unroll
            for (int kk = 0; kk < 4; kk++) {
                float w0 = W2[(size_t)(k + kk) * 384 + c];
                float w1 = W2[(size_t)(k + kk) * 384 + c + 128];
                float w2 = W2[(size_t)(k + kk) * 384 + c + 256];
                #pragma unroll
                for (int i = 0; i < 8; i++) {
                    float a = (&hv[i].x)[kk];
                    acc[i][0] = fmaf(a, w0, acc[i][0]);
                    acc[i][1] = fmaf(a, w1, acc[i][1]);
                    acc[i][2] = fmaf(a, w2, acc[i][2]);
                }
            }
        }
        #pragma unroll
        for (int i = 0; i < 8; i++)
            #pragma unroll
            for (int q = 0; q < 3; q++)
                mf[(nb + g * 8 + i) * 384 + c + 128 * q] = acc[i][q];
    }
}

// ---------------------------------------------------------------- CSR edge kernel
// 8-edge chunks with ne-GUARDED gathers (no wasted fetch on tail chunks).
// Epilogue folds v + dv*invsqrtH: writes vNew into dV buffer.
__global__ __launch_bounds__(256, 1) void k_edge9(const int* __restrict__ ei,
                                                  const float* __restrict__ evec,
                                                  const float* __restrict__ mf,
                                                  const float* __restrict__ v,
                                                  const float* __restrict__ Wr,
                                                  const float* __restrict__ br,
                                                  const int* __restrict__ offs,
                                                  const int* __restrict__ perm,
                                                  const float2* __restrict__ curc2,
                                                  float* __restrict__ s,
                                                  float* __restrict__ vNew,
                                                  int nN) {
    __shared__ float wrl[8064];
    for (int t = threadIdx.x; t < 8064; t += 256)
        wrl[t] = (t < 7680) ? Wr[t] : br[t - 7680];
    __syncthreads();

    const int lane = threadIdx.x & 63;
    const int wvi = __builtin_amdgcn_readfirstlane(threadIdx.x >> 6);
    const int nbase = blockIdx.x * 16 + wvi * 4;
    const float inv_sqrt3 = 0.57735026918962576451f;
    const float inv_sqrtH = 0.08838834764831845f;

    float brv[6];
    #pragma unroll
    for (int q = 0; q < 6; ++q) brv[q] = wrl[7680 + q * 64 + lane];

    for (int j = 0; j < 4; ++j) {
        const int n = nbase + j;
        if (n >= nN) break;
        const int beg = offs[n], end = offs[n + 1];

        float sa0 = 0.f, sa1 = 0.f;
        float dv00 = 0.f, dv10 = 0.f, dv20 = 0.f;
        float dv01 = 0.f, dv11 = 0.f, dv21 = 0.f;

        for (int i = beg; i < end; i += 8) {
            const int ne = end - i;   // wave-uniform
            int src[8];
            float ux[8], uy[8], uz[8], cur[8], prev[8], c2v[8];
            #pragma unroll
            for (int t = 0; t < 8; ++t) {
                int e = perm[i + t];
                float2 cc = curc2[i + t];
                cur[t] = cc.x; c2v[t] = cc.y; prev[t] = 0.f;
                src[t] = ei[e];
                float ex = evec[3 * e], ey = evec[3 * e + 1], ez = evec[3 * e + 2];
                float rn = 1.0f / sqrtf(ex * ex + ey * ey + ez * ez);
                ux[t] = ex * rn; uy[t] = ey * rn; uz[t] = ez * rn;
            }
            // prefetch gathers, GUARDED (wave-uniform branch) — no wasted fetch
            float gm[8][6], gv[8][6];
            #pragma unroll
            for (int t = 0; t < 8; ++t) {
                if (t < ne) {
                    const float* mfr = mf + (size_t)src[t] * 384 + lane;
                    const float* vr  = v  + (size_t)src[t] * 384 + lane;
                    #pragma unroll
                    for (int q = 0; q < 6; ++q) { gm[t][q] = mfr[q * 64]; gv[t][q] = vr[q * 64]; }
                }
            }
            float wf[8][6];
            #pragma unroll
            for (int t = 0; t < 8; ++t)
                #pragma unroll
                for (int q = 0; q < 6; ++q) wf[t][q] = brv[q];
            for (int rr = 0; rr < 20; ++rr) {
                float w6[6];
                #pragma unroll
                for (int q = 0; q < 6; ++q) w6[q] = wrl[rr * 384 + q * 64 + lane];
                #pragma unroll
                for (int t = 0; t < 8; ++t) {
                    float c = cur[t];
                    #pragma unroll
                    for (int q = 0; q < 6; ++q) wf[t][q] = fmaf(c, w6[q], wf[t][q]);
                    float nx = fmaf(c2v[t], c, -prev[t]);
                    prev[t] = c; cur[t] = nx;
                }
            }
            #pragma unroll
            for (int t = 0; t < 8; ++t) {
                if (t < ne) {
                    sa0 = fmaf(wf[t][0], gm[t][0], sa0);
                    sa1 = fmaf(wf[t][1], gm[t][1], sa1);
                    float a0 = wf[t][2] * gm[t][2] * inv_sqrt3;
                    float a1 = wf[t][3] * gm[t][3] * inv_sqrt3;
                    float b0 = wf[t][4] * gm[t][4];
                    float b1 = wf[t][5] * gm[t][5];
                    dv00 = fmaf(gv[t][0], a0, fmaf(ux[t], b0, dv00));
                    dv10 = fmaf(gv[t][2], a0, fmaf(uy[t], b0, dv10));
                    dv20 = fmaf(gv[t][4], a0, fmaf(uz[t], b0, dv20));
                    dv01 = fmaf(gv[t][1], a1, fmaf(ux[t], b1, dv01));
                    dv11 = fmaf(gv[t][3], a1, fmaf(uy[t], b1, dv11));
                    dv21 = fmaf(gv[t][5], a1, fmaf(uz[t], b1, dv21));
                }
            }
        }

        float* sp = s + (size_t)n * 128;
        sp[lane] += sa0;
        sp[64 + lane] += sa1;
        // vNew = v_own + dv * invsqrtH  (no race: gathers read old v rows of OTHER nodes' srcs,
        // and vNew is a separate buffer)
        const float* vo = v + (size_t)n * 384;
        float* dp = vNew + (size_t)n * 384;
        dp[lane]       = fmaf(dv00, inv_sqrtH, vo[lane]);
        dp[64 + lane]  = fmaf(dv01, inv_sqrtH, vo[64 + lane]);
        dp[128 + lane] = fmaf(dv10, inv_sqrtH, vo[128 + lane]);
        dp[192 + lane] = fmaf(dv11, inv_sqrtH, vo[192 + lane]);
        dp[256 + lane] = fmaf(dv20, inv_sqrtH, vo[256 + lane]);
        dp[320 + lane] = fmaf(dv21, inv_sqrtH, vo[320 + lane]);
    }
}

// ---------------------------------------------------------------- fused node update + next-layer mf
// vNew (= v + dv*invsqrtH) arrives precomputed from the edge kernel.
__global__ __launch_bounds__(256, 3) void k_updmf(float* __restrict__ s,
                                                  float* __restrict__ v,
                                                  const float* __restrict__ vNew,
                                                  const float* __restrict__ Wv,
                                                  const float* __restrict__ W1,
                                                  const float* __restrict__ b1,
                                                  const float* __restrict__ W2,
                                                  const float* __restrict__ b2,
                                                  const float* __restrict__ W1m,
                                                  const float* __restrict__ b1m,
                                                  const float* __restrict__ W2m,
                                                  const float* __restrict__ b2m,
                                                  float* __restrict__ mf) {
    __shared__ float sv[16 * 128];
    __shared__ float vn[16 * 384];
    __shared__ float vnl[16 * 128];
    __shared__ float u1[16 * 128];
    const int tid = threadIdx.x;
    const size_t nb = (size_t)blockIdx.x * 16;
    const float inv_sqrtH = 0.08838834764831845f;
    const float inv_sqrt2 = 0.70710678118654752440f;

    {
        const float4* s4 = (const float4*)(s + nb * 128);
        ((float4*)sv)[tid] = s4[tid];
        ((float4*)sv)[tid + 256] = s4[tid + 256];
        const float4* e4 = (const float4*)(vNew + nb * 384);
        #pragma unroll
        for (int t = 0; t < 6; ++t)
            ((float4*)vn)[tid + 256 * t] = e4[tid + 256 * t];
    }
    __syncthreads();
    const int c0 = tid & 63;
    const int ty = tid >> 6;
    float acc[4][3][4];
    {
        #pragma unroll
        for (int i = 0; i < 4; i++)
            #pragma unroll
            for (int d = 0; d < 3; d++)
                #pragma unroll
                for (int cc = 0; cc < 4; cc++) acc[i][d][cc] = 0.f;
        for (int k = 0; k < 128; k += 4) {
            float4 av[4][3];
            #pragma unroll
            for (int i = 0; i < 4; i++)
                #pragma unroll
                for (int d = 0; d < 3; d++)
                    av[i][d] = *(const float4*)&vn[(ty * 4 + i) * 384 + d * 128 + k];
            #pragma unroll
            for (int kk = 0; kk < 4; kk++) {
                float wc[4];
                #pragma unroll
                for (int cc = 0; cc < 4; cc++) wc[cc] = Wv[(size_t)(k + kk) * 256 + c0 + 64 * cc];
                #pragma unroll
                for (int i = 0; i < 4; i++)
                    #pragma unroll
                    for (int d = 0; d < 3; d++) {
                        float a = (&av[i][d].x)[kk];
                        #pragma unroll
                        for (int cc = 0; cc < 4; cc++)
                            acc[i][d][cc] = fmaf(a, wc[cc], acc[i][d][cc]);
                    }
            }
        }
    }
    float vdot[4][2];
    {
        #pragma unroll
        for (int i = 0; i < 4; i++)
            #pragma unroll
            for (int hh = 0; hh < 2; hh++) {
                float d0 = acc[i][0][hh] * acc[i][0][hh + 2] + acc[i][1][hh] * acc[i][1][hh + 2] +
                           acc[i][2][hh] * acc[i][2][hh + 2];
                vdot[i][hh] = d0 * inv_sqrtH;
                float n2 = acc[i][0][hh + 2] * acc[i][0][hh + 2] +
                           acc[i][1][hh + 2] * acc[i][1][hh + 2] +
                           acc[i][2][hh + 2] * acc[i][2][hh + 2];
                vnl[(ty * 4 + i) * 128 + c0 + 64 * hh] = sqrtf(n2 + 1e-12f);
            }
    }
    __syncthreads();
    {
        float a3[4][2];
        float bb0 = b1[c0], bb1 = b1[c0 + 64];
        #pragma unroll
        for (int i = 0; i < 4; i++) { a3[i][0] = bb0; a3[i][1] = bb1; }
        for (int k = 0; k < 128; k += 4) {
            float4 f[4];
            #pragma unroll
            for (int i = 0; i < 4; i++) f[i] = *(const float4*)&sv[(ty * 4 + i) * 128 + k];
            #pragma unroll
            for (int kk = 0; kk < 4; kk++) {
                float w0 = W1[(size_t)(k + kk) * 128 + c0];
                float w1 = W1[(size_t)(k + kk) * 128 + c0 + 64];
                #pragma unroll
                for (int i = 0; i < 4; i++) {
                    float a = (&f[i].x)[kk];
                    a3[i][0] = fmaf(a, w0, a3[i][0]);
                    a3[i][1] = fmaf(a, w1, a3[i][1]);
                }
            }
        }
        for (int k = 0; k < 128; k += 4) {
            float4 f[4];
            #pragma unroll
            for (int i = 0; i < 4; i++) f[i] = *(const float4*)&vnl[(ty * 4 + i) * 128 + k];
            #pragma unroll
            for (int kk = 0; kk < 4; kk++) {
                float w0 = W1[(size_t)(k + kk + 128) * 128 + c0];
                float w1 = W1[(size_t)(k + kk + 128) * 128 + c0 + 64];
                #pragma unroll
                for (int i = 0; i < 4; i++) {
                    float a = (&f[i].x)[kk];
                    a3[i][0] = fmaf(a, w0, a3[i][0]);
                    a3[i][1] = fmaf(a, w1, a3[i][1]);
                }
            }
        }
        #pragma unroll
        for (int i = 0; i < 4; i++) {
            u1[(ty * 4 + i) * 128 + c0] = silu_f(a3[i][0]);
            u1[(ty * 4 + i) * 128 + c0 + 64] = silu_f(a3[i][1]);
        }
    }
    __syncthreads();
    {
        float a4[4][6];
        #pragma unroll
        for (int q = 0; q < 6; q++) {
            float bb = b2[c0 + 64 * q];
            #pragma unroll
            for (int i = 0; i < 4; i++) a4[i][q] = bb;
        }
        for (int k = 0; k < 128; k += 4) {
            float4 uu[4];
            #pragma unroll
            for (int i = 0; i < 4; i++) uu[i] = *(const float4*)&u1[(ty * 4 + i) * 128 + k];
            #pragma unroll
            for (int kk = 0; kk < 4; kk++) {
                float w[6];
                #pragma unroll
                for (int q = 0; q < 6; q++) w[q] = W2[(size_t)(k + kk) * 384 + c0 + 64 * q];
                #pragma unroll
                for (int i = 0; i < 4; i++) {
                    float a = (&uu[i].x)[kk];
                    #pragma unroll
                    for (int q = 0; q < 6; q++) a4[i][q] = fmaf(a, w[q], a4[i][q]);
                }
            }
        }
        __syncthreads();   // all u1/sv reads done before sv overwrite
        #pragma unroll
        for (int i = 0; i < 4; i++) {
            int node = ty * 4 + i;
            size_t nr = nb + node;
            #pragma unroll
            for (int hh = 0; hh < 2; ++hh) {
                int h = c0 + 64 * hh;
                float a_ss = a4[i][hh], a_sv = a4[i][2 + hh], a_v = a4[i][4 + hh];
                float snew = sv[node * 128 + h] + (vdot[i][hh] * a_sv + a_ss) * inv_sqrt2;
                s[nr * 128 + h] = snew;
                sv[node * 128 + h] = snew;
                #pragma unroll
                for (int d = 0; d < 3; ++d)
                    v[nr * 384 + d * 128 + h] =
                        vn[node * 384 + d * 128 + h] + acc[i][d][hh] * a_v;
            }
        }
    }
    __syncthreads();
    // -------- fused mf(l+1)
    const int c = tid & 127;
    const int g = tid >> 7;
    {
        float am[8];
        float bb = b1m[c];
        #pragma unroll
        for (int i = 0; i < 8; i++) am[i] = bb;
        for (int k = 0; k < 128; k += 4) {
            float4 svv[8];
            #pragma unroll
            for (int i = 0; i < 8; i++) svv[i] = *(const float4*)&sv[(g * 8 + i) * 128 + k];
            #pragma unroll
            for (int kk = 0; kk < 4; kk++) {
                float w = W1m[(size_t)(k + kk) * 128 + c];
                #pragma unroll
                for (int i = 0; i < 8; i++) am[i] = fmaf((&svv[i].x)[kk], w, am[i]);
            }
        }
        #pragma unroll
        for (int i = 0; i < 8; i++) u1[(g * 8 + i) * 128 + c] = silu_f(am[i]);
    }
    __syncthreads();
    {
        float am[8][3];
        #pragma unroll
        for (int q = 0; q < 3; q++) {
            float bb = b2m[c + 128 * q];
            #pragma unroll
            for (int i = 0; i < 8; i++) am[i][q] = bb;
        }
        for (int k = 0; k < 128; k += 4) {
            float4 hv[8];
            #pragma unroll
            for (int i = 0; i < 8; i++) hv[i] = *(const float4*)&u1[(g * 8 + i) * 128 + k];
            #pragma unroll
            for (int kk = 0; kk < 4; kk++) {
                float w0 = W2m[(size_t)(k + kk) * 384 + c];
                float w1 = W2m[(size_t)(k + kk) * 384 + c + 128];
                float w2 = W2m[(size_t)(k + kk) * 384 + c + 256];
                #pragma unroll
                for (int i = 0; i < 8; i++) {
                    float a = (&hv[i].x)[kk];
                    am[i][0] = fmaf(a, w0, am[i][0]);
                    am[i][1] = fmaf(a, w1, am[i][1]);
                    am[i][2] = fmaf(a, w2, am[i][2]);
                }
            }
        }
        #pragma unroll
        for (int i = 0; i < 8; i++)
            #pragma unroll
            for (int q = 0; q < 3; q++)
                mf[(nb + g * 8 + i) * 384 + c + 128 * q] = am[i][q];
    }
}

// ---------------------------------------------------------------- fused final update + output head
__global__ __launch_bounds__(256, 3) void k_updout(const float* __restrict__ s,
                                                   const float* __restrict__ vNew,
                                                   const float* __restrict__ Wv,
                                                   const float* __restrict__ W1,
                                                   const float* __restrict__ b1,
                                                   const float* __restrict__ W2,
                                                   const float* __restrict__ b2,
                                                   const float* __restrict__ ow1,
                                                   const float* __restrict__ ob1,
                                                   const float* __restrict__ ow2,
                                                   const float* __restrict__ ob2,
                                                   float* __restrict__ out, int nNodes) {
    __shared__ float sv[16 * 128];
    __shared__ float vn[16 * 384];
    __shared__ float vnl[16 * 128];
    __shared__ float u1[16 * 128];
    __shared__ float red[4];
    const int tid = threadIdx.x;
    const size_t nb = (size_t)blockIdx.x * 16;
    const float inv_sqrtH = 0.08838834764831845f;
    const float inv_sqrt2 = 0.70710678118654752440f;

    {
        const float4* s4 = (const float4*)(s + nb * 128);
        ((float4*)sv)[tid] = s4[tid];
        ((float4*)sv)[tid + 256] = s4[tid + 256];
        const float4* e4 = (const float4*)(vNew + nb * 384);
        #pragma unroll
        for (int t = 0; t < 6; ++t)
            ((float4*)vn)[tid + 256 * t] = e4[tid + 256 * t];
    }
    __syncthreads();
    const int c0 = tid & 63;
    const int ty = tid >> 6;
    float acc[4][3][4];
    {
        #pragma unroll
        for (int i = 0; i < 4; i++)
            #pragma unroll
            for (int d = 0; d < 3; d++)
                #pragma unroll
                for (int cc = 0; cc < 4; cc++) acc[i][d][cc] = 0.f;
        for (int k = 0; k < 128; k += 4) {
            float4 av[4][3];
            #pragma unroll
            for (int i = 0; i < 4; i++)
                #pragma unroll
                for (int d = 0; d < 3; d++)
                    av[i][d] = *(const float4*)&vn[(ty * 4 + i) * 384 + d * 128 + k];
            #pragma unroll
            for (int kk = 0; kk < 4; kk++) {
                float wc[4];
                #pragma unroll
                for (int cc = 0; cc < 4; cc++) wc[cc] = Wv[(size_t)(k + kk) * 256 + c0 + 64 * cc];
                #pragma unroll
                for (int i = 0; i < 4; i++)
                    #pragma unroll
                    for (int d = 0; d < 3; d++) {
                        float a = (&av[i][d].x)[kk];
                        #pragma unroll
                        for (int cc = 0; cc < 4; cc++)
                            acc[i][d][cc] = fmaf(a, wc[cc], acc[i][d][cc]);
                    }
            }
        }
    }
    float vdot[4][2];
    {
        #pragma unroll
        for (int i = 0; i < 4; i++)
            #pragma unroll
            for (int hh = 0; hh < 2; hh++) {
                float d0 = acc[i][0][hh] * acc[i][0][hh + 2] + acc[i][1][hh] * acc[i][1][hh + 2] +
                           acc[i][2][hh] * acc[i][2][hh + 2];
                vdot[i][hh] = d0 * inv_sqrtH;
                float n2 = acc[i][0][hh + 2] * acc[i][0][hh + 2] +
                           acc[i][1][hh + 2] * acc[i][1][hh + 2] +
                           acc[i][2][hh + 2] * acc[i][2][hh + 2];
                vnl[(ty * 4 + i) * 128 + c0 + 64 * hh] = sqrtf(n2 + 1e-12f);
            }
    }
    __syncthreads();
    {
        float a3[4][2];
        float bb0 = b1[c0], bb1 = b1[c0 + 64];
        #pragma unroll
        for (int i = 0; i < 4; i++) { a3[i][0] = bb0; a3[i][1] = bb1; }
        for (int k = 0; k < 128; k += 4) {
            float4 f[4];
            #pragma unroll
            for (int i = 0; i < 4; i++) f[i] = *(const float4*)&sv[(ty * 4 + i) * 128 + k];
            #pragma unroll
            for (int kk = 0; kk < 4; kk++) {
                float w0 = W1[(size_t)(k + kk) * 128 + c0];
                float w1 = W1[(size_t)(k + kk) * 128 + c0 + 64];
                #pragma unroll
                for (int i = 0; i < 4; i++) {
                    float a = (&f[i].x)[kk];
                    a3[i][0] = fmaf(a, w0, a3[i][0]);
                    a3[i][1] = fmaf(a, w1, a3[i][1]);
                }
            }
        }
        for (int k = 0; k < 128; k += 4) {
            float4 f[4];
            #pragma unroll
            for (int i = 0; i < 4; i++) f[i] = *(const float4*)&vnl[(ty * 4 + i) * 128 + k];
            #pragma unroll
            for (int kk = 0; kk < 4; kk++) {
                float w0 = W1[(size_t)(k + kk + 128) * 128 + c0];
                float w1 = W1[(size_t)(k + kk + 128) * 128 + c0 + 64];
                #pragma unroll
                for (int i = 0; i < 4; i++) {
                    float a = (&f[i].x)[kk];
                    a3[i][0] = fmaf(a, w0, a3[i][0]);
                    a3[i][1] = fmaf(a, w1, a3[i][1]);
                }
            }
        }
        #pragma unroll
        for (int i = 0; i < 4; i++) {
            u1[(ty * 4 + i) * 128 + c0] = silu_f(a3[i][0]);
            u1[(ty * 4 + i) * 128 + c0 + 64] = silu_f(a3[i][1]);
        }
    }
    __syncthreads();
    {
        float a4[4][6];
        #pragma unroll
        for (int q = 0; q < 6; q++) {
            float bb = b2[c0 + 64 * q];
            #pragma unroll
            for (int i = 0; i < 4; i++) a4[i][q] = bb;
        }
        for (int k = 0; k < 128; k += 4) {
            float4 uu[4];
            #pragma unroll
            for (int i = 0; i < 4; i++) uu[i] = *(const float4*)&u1[(ty * 4 + i) * 128 + k];
            #pragma unroll
            for (int kk = 0; kk < 4; kk++) {
                float w[6];
                #pragma unroll
                for (int q = 0; q < 6; q++) w[q] = W2[(size_t)(k + kk) * 384 + c0 + 64 * q];
                #pragma unroll
                for (int i = 0; i < 4; i++) {
                    float a = (&uu[i].x)[kk];
                    #pragma unroll
                    for (int q = 0; q < 6; q++) a4[i][q] = fmaf(a, w[q], a4[i][q]);
                }
            }
        }
        __syncthreads();
        #pragma unroll
        for (int i = 0; i < 4; i++) {
            int node = ty * 4 + i;
            #pragma unroll
            for (int hh = 0; hh < 2; ++hh) {
                int h = c0 + 64 * hh;
                sv[node * 128 + h] = sv[node * 128 + h] +
                                     (vdot[i][hh] * a4[i][2 + hh] + a4[i][hh]) * inv_sqrt2;
            }
        }
    }
    __syncthreads();
    {
        float ao[4];
        float bb = ob1[c0];
        #pragma unroll
        for (int i = 0; i < 4; i++) ao[i] = bb;
        for (int k = 0; k < 128; k += 4) {
            float4 f[4];
            #pragma unroll
            for (int i = 0; i < 4; i++) f[i] = *(const float4*)&sv[(ty * 4 + i) * 128 + k];
            #pragma unroll
            for (int kk = 0; kk < 4; kk++) {
                float w = ow1[(size_t)(k + kk) * 64 + c0];
                #pragma unroll
                for (int i = 0; i < 4; i++) ao[i] = fmaf((&f[i].x)[kk], w, ao[i]);
            }
        }
        float w2 = ow2[c0];
        float p = 0.f;
        #pragma unroll
        for (int i = 0; i < 4; i++) p += silu_f(ao[i]) * w2;
        #pragma unroll
        for (int off = 32; off > 0; off >>= 1) p += __shfl_down(p, off, 64);
        if (c0 == 0) red[ty] = p;
        __syncthreads();
        if (tid == 0) {
            float val = (red[0] + red[1] + red[2] + red[3]) * (1.0f / (float)nNodes);
            if (blockIdx.x == 0) val += ob2[0];
            atomicAdd(out, val);
        }
    }
}

// ----------------------------------------------------------------
extern "C" void kernel_launch(void* const* d_in, const int* in_sizes, int n_in,
                              void* d_out, int out_size, void* d_ws, size_t ws_size,
                              hipStream_t stream) {
    const int*   z     = (const int*)d_in[0];
    const int*   ei    = (const int*)d_in[1];
    const float* edist = (const float*)d_in[2];
    const float* evec  = (const float*)d_in[3];
    const float* emb   = (const float*)d_in[4];
    const float* mw1   = (const float*)d_in[5];
    const float* mb1   = (const float*)d_in[6];
    const float* mw2   = (const float*)d_in[7];
    const float* mb2   = (const float*)d_in[8];
    const float* rw    = (const float*)d_in[9];
    const float* rbb   = (const float*)d_in[10];
    const float* uvw   = (const float*)d_in[11];
    const float* uw1   = (const float*)d_in[12];
    const float* ub1   = (const float*)d_in[13];
    const float* uw2   = (const float*)d_in[14];
    const float* ub2   = (const float*)d_in[15];
    const float* ow1   = (const float*)d_in[16];
    const float* ob1   = (const float*)d_in[17];
    const float* ow2   = (const float*)d_in[18];
    const float* ob2   = (const float*)d_in[19];

    const int N = in_sizes[0];
    const int E = in_sizes[2];
    const int Ep = E + 8;   // pad for 8-edge chunk over-read

    const size_t need = ((size_t)N * 1280 + (N + 1) + Ep) * 4 + (size_t)Ep * 8;
    hipMemsetAsync(d_out, 0, out_size * sizeof(float), stream);
    if (ws_size < need) return;

    float* ws = (float*)d_ws;
    float*  s     = ws;
    float*  v     = s + (size_t)N * 128;
    float*  mf    = v + (size_t)N * 384;
    float*  vNew  = mf + (size_t)N * 384;
    int*    offs  = (int*)(vNew + (size_t)N * 384);
    int*    perm  = offs + (N + 1);
    float2* curc2 = (float2*)(perm + Ep);
    int*    cnt   = (int*)curc2;     // build-time aliases
    int*    cur   = cnt + N;
    int*    btot  = cur + N;
    int*    btot2 = btot + 64;

    hipMemsetAsync(v, 0, (size_t)N * 384 * sizeof(float), stream);
    hipMemsetAsync(cnt, 0, (size_t)2 * N * sizeof(int), stream);

    const int nbScan = (N + 1023) / 1024;
    k_count<<<(E + 255) / 256, 256, 0, stream>>>(ei, cnt, E);
    k_scan_blk<<<nbScan, 1024, 0, stream>>>(cnt, offs, btot, N);
    k_scan_top<<<1, 64, 0, stream>>>(btot, btot2, nbScan, offs + N);
    k_scan_add<<<(N + 255) / 256, 256, 0, stream>>>(offs, btot2, N);
    k_fill<<<(E + 255) / 256, 256, 0, stream>>>(ei, offs, cur, perm, E);
    k_prep<<<(Ep + 255) / 256, 256, 0, stream>>>(edist, perm, curc2, E, Ep);

    k_initmf<<<N / 16, 256, 0, stream>>>(z, emb, s, mw1, mb1, mw2, mb2, mf);

    for (int l = 0; l < 3; ++l) {
        k_edge9<<<(N + 15) / 16, 256, 0, stream>>>(ei, evec, mf, v,
                                                   rw + (size_t)l * 7680, rbb + l * 384,
                                                   offs, perm, curc2, s, vNew, N);
        if (l < 2) {
            k_updmf<<<N / 16, 256, 0, stream>>>(s, v, vNew, uvw + (size_t)l * 32768,
                                                uw1 + (size_t)l * 32768, ub1 + l * 128,
                                                uw2 + (size_t)l * 49152, ub2 + l * 384,
                                                mw1 + (size_t)(l + 1) * 16384, mb1 + (l + 1) * 128,
                                                mw2 + (size_t)(l + 1) * 49152, mb2 + (l + 1) * 384,
                                                mf);
        } else {
            k_updout<<<N / 16, 256, 0, stream>>>(s, vNew, uvw + (size_t)l * 32768,
                                                 uw1 + (size_t)l * 32768, ub1 + l * 128,
                                                 uw2 + (size_t)l * 49152, ub2 + l * 384,
                                                 ow1, ob1, ow2, ob2, (float*)d_out, N);
        }
    }
}

// Round 13
// 2764.258 us; speedup vs baseline: 1.1149x; 1.1149x over previous
//
#include <hip/hip_runtime.h>
#include <hip/hip_bf16.h>
#include <math.h>

__device__ __forceinline__ float silu_f(float x) { return x / (1.0f + expf(-x)); }

// ---------------------------------------------------------------- CSR build
__global__ __launch_bounds__(256) void k_count(const int* __restrict__ ei, int* __restrict__ cnt,
                                               int nE) {
    int e = blockIdx.x * 256 + threadIdx.x;
    if (e < nE) atomicAdd(&cnt[ei[nE + e]], 1);
}

__global__ __launch_bounds__(1024) void k_scan_blk(const int* __restrict__ cnt,
                                                   int* __restrict__ offs,
                                                   int* __restrict__ btot, int N) {
    __shared__ int tmp[1024];
    const int tid = threadIdx.x;
    int i = blockIdx.x * 1024 + tid;
    int val = (i < N) ? cnt[i] : 0;
    tmp[tid] = val;
    __syncthreads();
    for (int off = 1; off < 1024; off <<= 1) {
        int t = (tid >= off) ? tmp[tid - off] : 0;
        __syncthreads();
        tmp[tid] += t;
        __syncthreads();
    }
    if (i < N) offs[i] = tmp[tid] - val;
    if (tid == 1023) btot[blockIdx.x] = tmp[1023];
}

__global__ void k_scan_top(const int* __restrict__ btot, int* __restrict__ btot2,
                           int nb, int* __restrict__ offsN) {
    int tid = threadIdx.x;
    int v = (tid < nb) ? btot[tid] : 0;
    int orig = v;
    #pragma unroll
    for (int off = 1; off < 64; off <<= 1) {
        int u = __shfl_up(v, off, 64);
        if (tid >= off) v += u;
    }
    btot2[tid] = v - orig;
    if (tid == 63) *offsN = v;
}

__global__ __launch_bounds__(256) void k_scan_add(int* __restrict__ offs,
                                                  const int* __restrict__ btot2, int N) {
    int i = blockIdx.x * 256 + threadIdx.x;
    if (i < N) offs[i] += btot2[i >> 10];
}

__global__ __launch_bounds__(256) void k_fill(const int* __restrict__ ei,
                                              const int* __restrict__ offs,
                                              int* __restrict__ cur, int* __restrict__ perm,
                                              int nE) {
    int e = blockIdx.x * 256 + threadIdx.x;
    if (e < nE) {
        int d = ei[nE + e];
        int p = atomicAdd(&cur[d], 1);
        perm[offs[d] + p] = e;
    }
}

// ---------------------------------------------------------------- per-edge trig precompute
__global__ __launch_bounds__(256) void k_prep(const float* __restrict__ edist,
                                              int* __restrict__ perm,
                                              float2* __restrict__ curc2,
                                              int nE, int nEpad) {
    int i = blockIdx.x * 256 + threadIdx.x;
    if (i >= nEpad) return;
    if (i >= nE) { perm[i] = 0; curc2[i] = make_float2(0.f, 0.f); return; }
    int e = perm[i];
    float dd = edist[e];
    float t = 0.62831853071795864769f * dd;  // pi*d/5
    float cs = cosf(t), sn = sinf(t);
    float cosc = (dd <= 5.0f) ? (0.5f * (cs + 1.0f)) : 0.0f;
    float ic = cosc / dd;
    curc2[i] = make_float2(sn * ic, 2.0f * cs);
}

// ---------------------------------------------------------------- fused init + layer-0 mf
__global__ __launch_bounds__(256, 4) void k_initmf(const int* __restrict__ z,
                                                   const float* __restrict__ emb,
                                                   float* __restrict__ s,
                                                   const float* __restrict__ W1,
                                                   const float* __restrict__ b1,
                                                   const float* __restrict__ W2,
                                                   const float* __restrict__ b2,
                                                   float* __restrict__ mf) {
    __shared__ float s_t[16 * 128];
    __shared__ float h_t[16 * 128];
    const int tid = threadIdx.x;
    const size_t nb = (size_t)blockIdx.x * 16;
    {
        float4* sg = (float4*)(s + nb * 128);
        #pragma unroll
        for (int r = 0; r < 2; ++r) {
            int j = tid + 256 * r;
            int node = j >> 5, c4 = j & 31;
            float4 val = ((const float4*)emb)[(size_t)z[nb + node] * 32 + c4];
            ((float4*)s_t)[j] = val;
            sg[j] = val;
        }
    }
    __syncthreads();
    const int c = tid & 127;
    const int g = tid >> 7;
    {
        float acc[8];
        float bb = b1[c];
        #pragma unroll
        for (int i = 0; i < 8; i++) acc[i] = bb;
        for (int k = 0; k < 128; k += 4) {
            float4 sv[8];
            #pragma unroll
            for (int i = 0; i < 8; i++) sv[i] = *(const float4*)&s_t[(g * 8 + i) * 128 + k];
            #pragma unroll
            for (int kk = 0; kk < 4; kk++) {
                float w = W1[(size_t)(k + kk) * 128 + c];
                #pragma unroll
                for (int i = 0; i < 8; i++) acc[i] = fmaf((&sv[i].x)[kk], w, acc[i]);
            }
        }
        #pragma unroll
        for (int i = 0; i < 8; i++) h_t[(g * 8 + i) * 128 + c] = silu_f(acc[i]);
    }
    __syncthreads();
    {
        float acc[8][3];
        #pragma unroll
        for (int q = 0; q < 3; q++) {
            float bb = b2[c + 128 * q];
            #pragma unroll
            for (int i = 0; i < 8; i++) acc[i][q] = bb;
        }
        for (int k = 0; k < 128; k += 4) {
            float4 hv[8];
            #pragma unroll
            for (int i = 0; i < 8; i++) hv[i] = *(const float4*)&h_t[(g * 8 + i) * 128 + k];
            #pragma unroll
            for (int kk = 0; kk < 4; kk++) {
                float w0 = W2[(size_t)(k + kk) * 384 + c];
                float w1 = W2[(size_t)(k + kk) * 384 + c + 128];
                float w2 = W2[(size_t)(k + kk) * 384 + c + 256];
                #pragma unroll
                for (int i = 0; i < 8; i++) {
                    float a = (&hv[i].x)[kk];
                    acc[i][0] = fmaf(a, w0, acc[i][0]);
                    acc[i][1] = fmaf(a, w1, acc[i][1]);
                    acc[i][2] = fmaf(a, w2, acc[i][2]);
                }
            }
        }
        #pragma unroll
        for (int i = 0; i < 8; i++)
            #pragma unroll
            for (int q = 0; q < 3; q++)
                mf[(nb + g * 8 + i) * 384 + c + 128 * q] = acc[i][q];
    }
}

// ---------------------------------------------------------------- CSR edge kernel
// 8-edge chunks; tail slots CLAMPED to the node's last edge (branchless dedup:
// dup gathers hit L1/L2, no wasted HBM fetch, prefetch stays one load clause).
// Epilogue folds v + dv*invsqrtH into vNew.
__global__ __launch_bounds__(256, 1) void k_edge10(const int* __restrict__ ei,
                                                   const float* __restrict__ evec,
                                                   const float* __restrict__ mf,
                                                   const float* __restrict__ v,
                                                   const float* __restrict__ Wr,
                                                   const float* __restrict__ br,
                                                   const int* __restrict__ offs,
                                                   const int* __restrict__ perm,
                                                   const float2* __restrict__ curc2,
                                                   float* __restrict__ s,
                                                   float* __restrict__ vNew,
                                                   int nN) {
    __shared__ float wrl[8064];
    for (int t = threadIdx.x; t < 8064; t += 256)
        wrl[t] = (t < 7680) ? Wr[t] : br[t - 7680];
    __syncthreads();

    const int lane = threadIdx.x & 63;
    const int wvi = __builtin_amdgcn_readfirstlane(threadIdx.x >> 6);
    const int nbase = blockIdx.x * 16 + wvi * 4;
    const float inv_sqrt3 = 0.57735026918962576451f;
    const float inv_sqrtH = 0.08838834764831845f;

    float brv[6];
    #pragma unroll
    for (int q = 0; q < 6; ++q) brv[q] = wrl[7680 + q * 64 + lane];

    for (int j = 0; j < 4; ++j) {
        const int n = nbase + j;
        if (n >= nN) break;
        const int beg = offs[n], end = offs[n + 1];

        float sa0 = 0.f, sa1 = 0.f;
        float dv00 = 0.f, dv10 = 0.f, dv20 = 0.f;
        float dv01 = 0.f, dv11 = 0.f, dv21 = 0.f;

        for (int i = beg; i < end; i += 8) {
            const int ne = end - i;   // wave-uniform, >=1
            // meta: tail slots clamp to the last live slot (s_cselect, no branch)
            int src[8];
            float ux[8], uy[8], uz[8], cur[8], prev[8], c2v[8];
            #pragma unroll
            for (int t = 0; t < 8; ++t) {
                int ii = i + ((t < ne) ? t : (ne - 1));
                int e = perm[ii];
                float2 cc = curc2[ii];
                cur[t] = cc.x; c2v[t] = cc.y; prev[t] = 0.f;
                src[t] = ei[e];
                float ex = evec[3 * e], ey = evec[3 * e + 1], ez = evec[3 * e + 2];
                float rn = 1.0f / sqrtf(ex * ex + ey * ey + ez * ez);
                ux[t] = ex * rn; uy[t] = ey * rn; uz[t] = ez * rn;
            }
            // prefetch ALL gathers unguarded (dup tail addrs -> cache hits)
            float gm[8][6], gv[8][6];
            #pragma unroll
            for (int t = 0; t < 8; ++t) {
                const float* mfr = mf + (size_t)src[t] * 384 + lane;
                const float* vr  = v  + (size_t)src[t] * 384 + lane;
                #pragma unroll
                for (int q = 0; q < 6; ++q) { gm[t][q] = mfr[q * 64]; gv[t][q] = vr[q * 64]; }
            }
            float wf[8][6];
            #pragma unroll
            for (int t = 0; t < 8; ++t)
                #pragma unroll
                for (int q = 0; q < 6; ++q) wf[t][q] = brv[q];
            for (int rr = 0; rr < 20; ++rr) {
                float w6[6];
                #pragma unroll
                for (int q = 0; q < 6; ++q) w6[q] = wrl[rr * 384 + q * 64 + lane];
                #pragma unroll
                for (int t = 0; t < 8; ++t) {
                    float c = cur[t];
                    #pragma unroll
                    for (int q = 0; q < 6; ++q) wf[t][q] = fmaf(c, w6[q], wf[t][q]);
                    float nx = fmaf(c2v[t], c, -prev[t]);
                    prev[t] = c; cur[t] = nx;
                }
            }
            #pragma unroll
            for (int t = 0; t < 8; ++t) {
                if (t < ne) {
                    sa0 = fmaf(wf[t][0], gm[t][0], sa0);
                    sa1 = fmaf(wf[t][1], gm[t][1], sa1);
                    float a0 = wf[t][2] * gm[t][2] * inv_sqrt3;
                    float a1 = wf[t][3] * gm[t][3] * inv_sqrt3;
                    float b0 = wf[t][4] * gm[t][4];
                    float b1 = wf[t][5] * gm[t][5];
                    dv00 = fmaf(gv[t][0], a0, fmaf(ux[t], b0, dv00));
                    dv10 = fmaf(gv[t][2], a0, fmaf(uy[t], b0, dv10));
                    dv20 = fmaf(gv[t][4], a0, fmaf(uz[t], b0, dv20));
                    dv01 = fmaf(gv[t][1], a1, fmaf(ux[t], b1, dv01));
                    dv11 = fmaf(gv[t][3], a1, fmaf(uy[t], b1, dv11));
                    dv21 = fmaf(gv[t][5], a1, fmaf(uz[t], b1, dv21));
                }
            }
        }

        float* sp = s + (size_t)n * 128;
        sp[lane] += sa0;
        sp[64 + lane] += sa1;
        const float* vo = v + (size_t)n * 384;
        float* dp = vNew + (size_t)n * 384;
        dp[lane]       = fmaf(dv00, inv_sqrtH, vo[lane]);
        dp[64 + lane]  = fmaf(dv01, inv_sqrtH, vo[64 + lane]);
        dp[128 + lane] = fmaf(dv10, inv_sqrtH, vo[128 + lane]);
        dp[192 + lane] = fmaf(dv11, inv_sqrtH, vo[192 + lane]);
        dp[256 + lane] = fmaf(dv20, inv_sqrtH, vo[256 + lane]);
        dp[320 + lane] = fmaf(dv21, inv_sqrtH, vo[320 + lane]);
    }
}

// ---------------------------------------------------------------- fused node update + next-layer mf
__global__ __launch_bounds__(256, 3) void k_updmf(float* __restrict__ s,
                                                  float* __restrict__ v,
                                                  const float* __restrict__ vNew,
                                                  const float* __restrict__ Wv,
                                                  const float* __restrict__ W1,
                                                  const float* __restrict__ b1,
                                                  const float* __restrict__ W2,
                                                  const float* __restrict__ b2,
                                                  const float* __restrict__ W1m,
                                                  const float* __restrict__ b1m,
                                                  const float* __restrict__ W2m,
                                                  const float* __restrict__ b2m,
                                                  float* __restrict__ mf) {
    __shared__ float sv[16 * 128];
    __shared__ float vn[16 * 384];
    __shared__ float vnl[16 * 128];
    __shared__ float u1[16 * 128];
    const int tid = threadIdx.x;
    const size_t nb = (size_t)blockIdx.x * 16;
    const float inv_sqrtH = 0.08838834764831845f;
    const float inv_sqrt2 = 0.70710678118654752440f;

    {
        const float4* s4 = (const float4*)(s + nb * 128);
        ((float4*)sv)[tid] = s4[tid];
        ((float4*)sv)[tid + 256] = s4[tid + 256];
        const float4* e4 = (const float4*)(vNew + nb * 384);
        #pragma unroll
        for (int t = 0; t < 6; ++t)
            ((float4*)vn)[tid + 256 * t] = e4[tid + 256 * t];
    }
    __syncthreads();
    const int c0 = tid & 63;
    const int ty = tid >> 6;
    float acc[4][3][4];
    {
        #pragma unroll
        for (int i = 0; i < 4; i++)
            #pragma unroll
            for (int d = 0; d < 3; d++)
                #pragma unroll
                for (int cc = 0; cc < 4; cc++) acc[i][d][cc] = 0.f;
        for (int k = 0; k < 128; k += 4) {
            float4 av[4][3];
            #pragma unroll
            for (int i = 0; i < 4; i++)
                #pragma unroll
                for (int d = 0; d < 3; d++)
                    av[i][d] = *(const float4*)&vn[(ty * 4 + i) * 384 + d * 128 + k];
            #pragma unroll
            for (int kk = 0; kk < 4; kk++) {
                float wc[4];
                #pragma unroll
                for (int cc = 0; cc < 4; cc++) wc[cc] = Wv[(size_t)(k + kk) * 256 + c0 + 64 * cc];
                #pragma unroll
                for (int i = 0; i < 4; i++)
                    #pragma unroll
                    for (int d = 0; d < 3; d++) {
                        float a = (&av[i][d].x)[kk];
                        #pragma unroll
                        for (int cc = 0; cc < 4; cc++)
                            acc[i][d][cc] = fmaf(a, wc[cc], acc[i][d][cc]);
                    }
            }
        }
    }
    float vdot[4][2];
    {
        #pragma unroll
        for (int i = 0; i < 4; i++)
            #pragma unroll
            for (int hh = 0; hh < 2; hh++) {
                float d0 = acc[i][0][hh] * acc[i][0][hh + 2] + acc[i][1][hh] * acc[i][1][hh + 2] +
                           acc[i][2][hh] * acc[i][2][hh + 2];
                vdot[i][hh] = d0 * inv_sqrtH;
                float n2 = acc[i][0][hh + 2] * acc[i][0][hh + 2] +
                           acc[i][1][hh + 2] * acc[i][1][hh + 2] +
                           acc[i][2][hh + 2] * acc[i][2][hh + 2];
                vnl[(ty * 4 + i) * 128 + c0 + 64 * hh] = sqrtf(n2 + 1e-12f);
            }
    }
    __syncthreads();
    {
        float a3[4][2];
        float bb0 = b1[c0], bb1 = b1[c0 + 64];
        #pragma unroll
        for (int i = 0; i < 4; i++) { a3[i][0] = bb0; a3[i][1] = bb1; }
        for (int k = 0; k < 128; k += 4) {
            float4 f[4];
            #pragma unroll
            for (int i = 0; i < 4; i++) f[i] = *(const float4*)&sv[(ty * 4 + i) * 128 + k];
            #pragma unroll
            for (int kk = 0; kk < 4; kk++) {
                float w0 = W1[(size_t)(k + kk) * 128 + c0];
                float w1 = W1[(size_t)(k + kk) * 128 + c0 + 64];
                #pragma unroll
                for (int i = 0; i < 4; i++) {
                    float a = (&f[i].x)[kk];
                    a3[i][0] = fmaf(a, w0, a3[i][0]);
                    a3[i][1] = fmaf(a, w1, a3[i][1]);
                }
            }
        }
        for (int k = 0; k < 128; k += 4) {
            float4 f[4];
            #pragma unroll
            for (int i = 0; i < 4; i++) f[i] = *(const float4*)&vnl[(ty * 4 + i) * 128 + k];
            #pragma unroll
            for (int kk = 0; kk < 4; kk++) {
                float w0 = W1[(size_t)(k + kk + 128) * 128 + c0];
                float w1 = W1[(size_t)(k + kk + 128) * 128 + c0 + 64];
                #pragma unroll
                for (int i = 0; i < 4; i++) {
                    float a = (&f[i].x)[kk];
                    a3[i][0] = fmaf(a, w0, a3[i][0]);
                    a3[i][1] = fmaf(a, w1, a3[i][1]);
                }
            }
        }
        #pragma unroll
        for (int i = 0; i < 4; i++) {
            u1[(ty * 4 + i) * 128 + c0] = silu_f(a3[i][0]);
            u1[(ty * 4 + i) * 128 + c0 + 64] = silu_f(a3[i][1]);
        }
    }
    __syncthreads();
    {
        float a4[4][6];
        #pragma unroll
        for (int q = 0; q < 6; q++) {
            float bb = b2[c0 + 64 * q];
            #pragma unroll
            for (int i = 0; i < 4; i++) a4[i][q] = bb;
        }
        for (int k = 0; k < 128; k += 4) {
            float4 uu[4];
            #pragma unroll
            for (int i = 0; i < 4; i++) uu[i] = *(const float4*)&u1[(ty * 4 + i) * 128 + k];
            #pragma unroll
            for (int kk = 0; kk < 4; kk++) {
                float w[6];
                #pragma unroll
                for (int q = 0; q < 6; q++) w[q] = W2[(size_t)(k + kk) * 384 + c0 + 64 * q];
                #pragma unroll
                for (int i = 0; i < 4; i++) {
                    float a = (&uu[i].x)[kk];
                    #pragma unroll
                    for (int q = 0; q < 6; q++) a4[i][q] = fmaf(a, w[q], a4[i][q]);
                }
            }
        }
        __syncthreads();   // all u1/sv reads done before sv overwrite
        #pragma unroll
        for (int i = 0; i < 4; i++) {
            int node = ty * 4 + i;
            size_t nr = nb + node;
            #pragma unroll
            for (int hh = 0; hh < 2; ++hh) {
                int h = c0 + 64 * hh;
                float a_ss = a4[i][hh], a_sv = a4[i][2 + hh], a_v = a4[i][4 + hh];
                float snew = sv[node * 128 + h] + (vdot[i][hh] * a_sv + a_ss) * inv_sqrt2;
                s[nr * 128 + h] = snew;
                sv[node * 128 + h] = snew;
                #pragma unroll
                for (int d = 0; d < 3; ++d)
                    v[nr * 384 + d * 128 + h] =
                        vn[node * 384 + d * 128 + h] + acc[i][d][hh] * a_v;
            }
        }
    }
    __syncthreads();
    // -------- fused mf(l+1)
    const int c = tid & 127;
    const int g = tid >> 7;
    {
        float am[8];
        float bb = b1m[c];
        #pragma unroll
        for (int i = 0; i < 8; i++) am[i] = bb;
        for (int k = 0; k < 128; k += 4) {
            float4 svv[8];
            #pragma unroll
            for (int i = 0; i < 8; i++) svv[i] = *(const float4*)&sv[(g * 8 + i) * 128 + k];
            #pragma unroll
            for (int kk = 0; kk < 4; kk++) {
                float w = W1m[(size_t)(k + kk) * 128 + c];
                #pragma unroll
                for (int i = 0; i < 8; i++) am[i] = fmaf((&svv[i].x)[kk], w, am[i]);
            }
        }
        #pragma unroll
        for (int i = 0; i < 8; i++) u1[(g * 8 + i) * 128 + c] = silu_f(am[i]);
    }
    __syncthreads();
    {
        float am[8][3];
        #pragma unroll
        for (int q = 0; q < 3; q++) {
            float bb = b2m[c + 128 * q];
            #pragma unroll
            for (int i = 0; i < 8; i++) am[i][q] = bb;
        }
        for (int k = 0; k < 128; k += 4) {
            float4 hv[8];
            #pragma unroll
            for (int i = 0; i < 8; i++) hv[i] = *(const float4*)&u1[(g * 8 + i) * 128 + k];
            #pragma unroll
            for (int kk = 0; kk < 4; kk++) {
                float w0 = W2m[(size_t)(k + kk) * 384 + c];
                float w1 = W2m[(size_t)(k + kk) * 384 + c + 128];
                float w2 = W2m[(size_t)(k + kk) * 384 + c + 256];
                #pragma unroll
                for (int i = 0; i < 8; i++) {
                    float a = (&hv[i].x)[kk];
                    am[i][0] = fmaf(a, w0, am[i][0]);
                    am[i][1] = fmaf(a, w1, am[i][1]);
                    am[i][2] = fmaf(a, w2, am[i][2]);
                }
            }
        }
        #pragma unroll
        for (int i = 0; i < 8; i++)
            #pragma unroll
            for (int q = 0; q < 3; q++)
                mf[(nb + g * 8 + i) * 384 + c + 128 * q] = am[i][q];
    }
}

// ---------------------------------------------------------------- fused final update + output head
__global__ __launch_bounds__(256, 3) void k_updout(const float* __restrict__ s,
                                                   const float* __restrict__ vNew,
                                                   const float* __restrict__ Wv,
                                                   const float* __restrict__ W1,
                                                   const float* __restrict__ b1,
                                                   const float* __restrict__ W2,
                                                   const float* __restrict__ b2,
                                                   const float* __restrict__ ow1,
                                                   const float* __restrict__ ob1,
                                                   const float* __restrict__ ow2,
                                                   const float* __restrict__ ob2,
                                                   float* __restrict__ out, int nNodes) {
    __shared__ float sv[16 * 128];
    __shared__ float vn[16 * 384];
    __shared__ float vnl[16 * 128];
    __shared__ float u1[16 * 128];
    __shared__ float red[4];
    const int tid = threadIdx.x;
    const size_t nb = (size_t)blockIdx.x * 16;
    const float inv_sqrtH = 0.08838834764831845f;
    const float inv_sqrt2 = 0.70710678118654752440f;

    {
        const float4* s4 = (const float4*)(s + nb * 128);
        ((float4*)sv)[tid] = s4[tid];
        ((float4*)sv)[tid + 256] = s4[tid + 256];
        const float4* e4 = (const float4*)(vNew + nb * 384);
        #pragma unroll
        for (int t = 0; t < 6; ++t)
            ((float4*)vn)[tid + 256 * t] = e4[tid + 256 * t];
    }
    __syncthreads();
    const int c0 = tid & 63;
    const int ty = tid >> 6;
    float acc[4][3][4];
    {
        #pragma unroll
        for (int i = 0; i < 4; i++)
            #pragma unroll
            for (int d = 0; d < 3; d++)
                #pragma unroll
                for (int cc = 0; cc < 4; cc++) acc[i][d][cc] = 0.f;
        for (int k = 0; k < 128; k += 4) {
            float4 av[4][3];
            #pragma unroll
            for (int i = 0; i < 4; i++)
                #pragma unroll
                for (int d = 0; d < 3; d++)
                    av[i][d] = *(const float4*)&vn[(ty * 4 + i) * 384 + d * 128 + k];
            #pragma unroll
            for (int kk = 0; kk < 4; kk++) {
                float wc[4];
                #pragma unroll
                for (int cc = 0; cc < 4; cc++) wc[cc] = Wv[(size_t)(k + kk) * 256 + c0 + 64 * cc];
                #pragma unroll
                for (int i = 0; i < 4; i++)
                    #pragma unroll
                    for (int d = 0; d < 3; d++) {
                        float a = (&av[i][d].x)[kk];
                        #pragma unroll
                        for (int cc = 0; cc < 4; cc++)
                            acc[i][d][cc] = fmaf(a, wc[cc], acc[i][d][cc]);
                    }
            }
        }
    }
    float vdot[4][2];
    {
        #pragma unroll
        for (int i = 0; i < 4; i++)
            #pragma unroll
            for (int hh = 0; hh < 2; hh++) {
                float d0 = acc[i][0][hh] * acc[i][0][hh + 2] + acc[i][1][hh] * acc[i][1][hh + 2] +
                           acc[i][2][hh] * acc[i][2][hh + 2];
                vdot[i][hh] = d0 * inv_sqrtH;
                float n2 = acc[i][0][hh + 2] * acc[i][0][hh + 2] +
                           acc[i][1][hh + 2] * acc[i][1][hh + 2] +
                           acc[i][2][hh + 2] * acc[i][2][hh + 2];
                vnl[(ty * 4 + i) * 128 + c0 + 64 * hh] = sqrtf(n2 + 1e-12f);
            }
    }
    __syncthreads();
    {
        float a3[4][2];
        float bb0 = b1[c0], bb1 = b1[c0 + 64];
        #pragma unroll
        for (int i = 0; i < 4; i++) { a3[i][0] = bb0; a3[i][1] = bb1; }
        for (int k = 0; k < 128; k += 4) {
            float4 f[4];
            #pragma unroll
            for (int i = 0; i < 4; i++) f[i] = *(const float4*)&sv[(ty * 4 + i) * 128 + k];
            #pragma unroll
            for (int kk = 0; kk < 4; kk++) {
                float w0 = W1[(size_t)(k + kk) * 128 + c0];
                float w1 = W1[(size_t)(k + kk) * 128 + c0 + 64];
                #pragma unroll
                for (int i = 0; i < 4; i++) {
                    float a = (&f[i].x)[kk];
                    a3[i][0] = fmaf(a, w0, a3[i][0]);
                    a3[i][1] = fmaf(a, w1, a3[i][1]);
                }
            }
        }
        for (int k = 0; k < 128; k += 4) {
            float4 f[4];
            #pragma unroll
            for (int i = 0; i < 4; i++) f[i] = *(const float4*)&vnl[(ty * 4 + i) * 128 + k];
            #pragma unroll
            for (int kk = 0; kk < 4; kk++) {
                float w0 = W1[(size_t)(k + kk + 128) * 128 + c0];
                float w1 = W1[(size_t)(k + kk + 128) * 128 + c0 + 64];
                #pragma unroll
                for (int i = 0; i < 4; i++) {
                    float a = (&f[i].x)[kk];
                    a3[i][0] = fmaf(a, w0, a3[i][0]);
                    a3[i][1] = fmaf(a, w1, a3[i][1]);
                }
            }
        }
        #pragma unroll
        for (int i = 0; i < 4; i++) {
            u1[(ty * 4 + i) * 128 + c0] = silu_f(a3[i][0]);
            u1[(ty * 4 + i) * 128 + c0 + 64] = silu_f(a3[i][1]);
        }
    }
    __syncthreads();
    {
        float a4[4][6];
        #pragma unroll
        for (int q = 0; q < 6; q++) {
            float bb = b2[c0 + 64 * q];
            #pragma unroll
            for (int i = 0; i < 4; i++) a4[i][q] = bb;
        }
        for (int k = 0; k < 128; k += 4) {
            float4 uu[4];
            #pragma unroll
            for (int i = 0; i < 4; i++) uu[i] = *(const float4*)&u1[(ty * 4 + i) * 128 + k];
            #pragma unroll
            for (int kk = 0; kk < 4; kk++) {
                float w[6];
                #pragma unroll
                for (int q = 0; q < 6; q++) w[q] = W2[(size_t)(k + kk) * 384 + c0 + 64 * q];
                #pragma unroll
                for (int i = 0; i < 4; i++) {
                    float a = (&uu[i].x)[kk];
                    #pragma unroll
                    for (int q = 0; q < 6; q++) a4[i][q] = fmaf(a, w[q], a4[i][q]);
                }
            }
        }
        __syncthreads();
        #pragma unroll
        for (int i = 0; i < 4; i++) {
            int node = ty * 4 + i;
            #pragma unroll
            for (int hh = 0; hh < 2; ++hh) {
                int h = c0 + 64 * hh;
                sv[node * 128 + h] = sv[node * 128 + h] +
                                     (vdot[i][hh] * a4[i][2 + hh] + a4[i][hh]) * inv_sqrt2;
            }
        }
    }
    __syncthreads();
    {
        float ao[4];
        float bb = ob1[c0];
        #pragma unroll
        for (int i = 0; i < 4; i++) ao[i] = bb;
        for (int k = 0; k < 128; k += 4) {
            float4 f[4];
            #pragma unroll
            for (int i = 0; i < 4; i++) f[i] = *(const float4*)&sv[(ty * 4 + i) * 128 + k];
            #pragma unroll
            for (int kk = 0; kk < 4; kk++) {
                float w = ow1[(size_t)(k + kk) * 64 + c0];
                #pragma unroll
                for (int i = 0; i < 4; i++) ao[i] = fmaf((&f[i].x)[kk], w, ao[i]);
            }
        }
        float w2 = ow2[c0];
        float p = 0.f;
        #pragma unroll
        for (int i = 0; i < 4; i++) p += silu_f(ao[i]) * w2;
        #pragma unroll
        for (int off = 32; off > 0; off >>= 1) p += __shfl_down(p, off, 64);
        if (c0 == 0) red[ty] = p;
        __syncthreads();
        if (tid == 0) {
            float val = (red[0] + red[1] + red[2] + red[3]) * (1.0f / (float)nNodes);
            if (blockIdx.x == 0) val += ob2[0];
            atomicAdd(out, val);
        }
    }
}

// ----------------------------------------------------------------
extern "C" void kernel_launch(void* const* d_in, const int* in_sizes, int n_in,
                              void* d_out, int out_size, void* d_ws, size_t ws_size,
                              hipStream_t stream) {
    const int*   z     = (const int*)d_in[0];
    const int*   ei    = (const int*)d_in[1];
    const float* edist = (const float*)d_in[2];
    const float* evec  = (const float*)d_in[3];
    const float* emb   = (const float*)d_in[4];
    const float* mw1   = (const float*)d_in[5];
    const float* mb1   = (const float*)d_in[6];
    const float* mw2   = (const float*)d_in[7];
    const float* mb2   = (const float*)d_in[8];
    const float* rw    = (const float*)d_in[9];
    const float* rbb   = (const float*)d_in[10];
    const float* uvw   = (const float*)d_in[11];
    const float* uw1   = (const float*)d_in[12];
    const float* ub1   = (const float*)d_in[13];
    const float* uw2   = (const float*)d_in[14];
    const float* ub2   = (const float*)d_in[15];
    const float* ow1   = (const float*)d_in[16];
    const float* ob1   = (const float*)d_in[17];
    const float* ow2   = (const float*)d_in[18];
    const float* ob2   = (const float*)d_in[19];

    const int N = in_sizes[0];
    const int E = in_sizes[2];
    const int Ep = E + 8;

    const size_t need = ((size_t)N * 1280 + (N + 1) + Ep) * 4 + (size_t)Ep * 8;
    hipMemsetAsync(d_out, 0, out_size * sizeof(float), stream);
    if (ws_size < need) return;

    float* ws = (float*)d_ws;
    float*  s     = ws;
    float*  v     = s + (size_t)N * 128;
    float*  mf    = v + (size_t)N * 384;
    float*  vNew  = mf + (size_t)N * 384;
    int*    offs  = (int*)(vNew + (size_t)N * 384);
    int*    perm  = offs + (N + 1);
    float2* curc2 = (float2*)(perm + Ep);
    int*    cnt   = (int*)curc2;     // build-time aliases
    int*    cur   = cnt + N;
    int*    btot  = cur + N;
    int*    btot2 = btot + 64;

    hipMemsetAsync(v, 0, (size_t)N * 384 * sizeof(float), stream);
    hipMemsetAsync(cnt, 0, (size_t)2 * N * sizeof(int), stream);

    const int nbScan = (N + 1023) / 1024;
    k_count<<<(E + 255) / 256, 256, 0, stream>>>(ei, cnt, E);
    k_scan_blk<<<nbScan, 1024, 0, stream>>>(cnt, offs, btot, N);
    k_scan_top<<<1, 64, 0, stream>>>(btot, btot2, nbScan, offs + N);
    k_scan_add<<<(N + 255) / 256, 256, 0, stream>>>(offs, btot2, N);
    k_fill<<<(E + 255) / 256, 256, 0, stream>>>(ei, offs, cur, perm, E);
    k_prep<<<(Ep + 255) / 256, 256, 0, stream>>>(edist, perm, curc2, E, Ep);

    k_initmf<<<N / 16, 256, 0, stream>>>(z, emb, s, mw1, mb1, mw2, mb2, mf);

    for (int l = 0; l < 3; ++l) {
        k_edge10<<<(N + 15) / 16, 256, 0, stream>>>(ei, evec, mf, v,
                                                    rw + (size_t)l * 7680, rbb + l * 384,
                                                    offs, perm, curc2, s, vNew, N);
        if (l < 2) {
            k_updmf<<<N / 16, 256, 0, stream>>>(s, v, vNew, uvw + (size_t)l * 32768,
                                                uw1 + (size_t)l * 32768, ub1 + l * 128,
                                                uw2 + (size_t)l * 49152, ub2 + l * 384,
                                                mw1 + (size_t)(l + 1) * 16384, mb1 + (l + 1) * 128,
                                                mw2 + (size_t)(l + 1) * 49152, mb2 + (l + 1) * 384,
                                                mf);
        } else {
            k_updout<<<N / 16, 256, 0, stream>>>(s, vNew, uvw + (size_t)l * 32768,
                                                 uw1 + (size_t)l * 32768, ub1 + l * 128,
                                                 uw2 + (size_t)l * 49152, ub2 + l * 384,
                                                 ow1, ob1, ow2, ob2, (float*)d_out, N);
        }
    }
}

// Round 14
// 2749.644 us; speedup vs baseline: 1.1208x; 1.0053x over previous
//
#include <hip/hip_runtime.h>
#include <hip/hip_bf16.h>
#include <math.h>

__device__ __forceinline__ float silu_f(float x) { return x / (1.0f + expf(-x)); }

// ---------------------------------------------------------------- CSR build
__global__ __launch_bounds__(256) void k_count(const int* __restrict__ ei, int* __restrict__ cnt,
                                               int nE) {
    int e = blockIdx.x * 256 + threadIdx.x;
    if (e < nE) atomicAdd(&cnt[ei[nE + e]], 1);
}

__global__ __launch_bounds__(1024) void k_scan_blk(const int* __restrict__ cnt,
                                                   int* __restrict__ offs,
                                                   int* __restrict__ btot, int N) {
    __shared__ int tmp[1024];
    const int tid = threadIdx.x;
    int i = blockIdx.x * 1024 + tid;
    int val = (i < N) ? cnt[i] : 0;
    tmp[tid] = val;
    __syncthreads();
    for (int off = 1; off < 1024; off <<= 1) {
        int t = (tid >= off) ? tmp[tid - off] : 0;
        __syncthreads();
        tmp[tid] += t;
        __syncthreads();
    }
    if (i < N) offs[i] = tmp[tid] - val;
    if (tid == 1023) btot[blockIdx.x] = tmp[1023];
}

__global__ void k_scan_top(const int* __restrict__ btot, int* __restrict__ btot2,
                           int nb, int* __restrict__ offsN) {
    int tid = threadIdx.x;
    int v = (tid < nb) ? btot[tid] : 0;
    int orig = v;
    #pragma unroll
    for (int off = 1; off < 64; off <<= 1) {
        int u = __shfl_up(v, off, 64);
        if (tid >= off) v += u;
    }
    btot2[tid] = v - orig;
    if (tid == 63) *offsN = v;
}

__global__ __launch_bounds__(256) void k_scan_add(int* __restrict__ offs,
                                                  const int* __restrict__ btot2, int N) {
    int i = blockIdx.x * 256 + threadIdx.x;
    if (i < N) offs[i] += btot2[i >> 10];
}

__global__ __launch_bounds__(256) void k_fill(const int* __restrict__ ei,
                                              const int* __restrict__ offs,
                                              int* __restrict__ cur, int* __restrict__ perm,
                                              int nE) {
    int e = blockIdx.x * 256 + threadIdx.x;
    if (e < nE) {
        int d = ei[nE + e];
        int p = atomicAdd(&cur[d], 1);
        perm[offs[d] + p] = e;
    }
}

// ---------------------------------------------------------------- per-edge trig precompute
__global__ __launch_bounds__(256) void k_prep(const float* __restrict__ edist,
                                              int* __restrict__ perm,
                                              float2* __restrict__ curc2,
                                              int nE, int nEpad) {
    int i = blockIdx.x * 256 + threadIdx.x;
    if (i >= nEpad) return;
    if (i >= nE) { perm[i] = 0; curc2[i] = make_float2(0.f, 0.f); return; }
    int e = perm[i];
    float dd = edist[e];
    float t = 0.62831853071795864769f * dd;  // pi*d/5
    float cs = cosf(t), sn = sinf(t);
    float cosc = (dd <= 5.0f) ? (0.5f * (cs + 1.0f)) : 0.0f;
    float ic = cosc / dd;
    curc2[i] = make_float2(sn * ic, 2.0f * cs);
}

// ---------------------------------------------------------------- fused init + layer-0 mf
__global__ __launch_bounds__(256, 4) void k_initmf(const int* __restrict__ z,
                                                   const float* __restrict__ emb,
                                                   float* __restrict__ s,
                                                   const float* __restrict__ W1,
                                                   const float* __restrict__ b1,
                                                   const float* __restrict__ W2,
                                                   const float* __restrict__ b2,
                                                   float* __restrict__ mf) {
    __shared__ float s_t[16 * 128];
    __shared__ float h_t[16 * 128];
    const int tid = threadIdx.x;
    const size_t nb = (size_t)blockIdx.x * 16;
    {
        float4* sg = (float4*)(s + nb * 128);
        #pragma unroll
        for (int r = 0; r < 2; ++r) {
            int j = tid + 256 * r;
            int node = j >> 5, c4 = j & 31;
            float4 val = ((const float4*)emb)[(size_t)z[nb + node] * 32 + c4];
            ((float4*)s_t)[j] = val;
            sg[j] = val;
        }
    }
    __syncthreads();
    const int c = tid & 127;
    const int g = tid >> 7;
    {
        float acc[8];
        float bb = b1[c];
        #pragma unroll
        for (int i = 0; i < 8; i++) acc[i] = bb;
        for (int k = 0; k < 128; k += 4) {
            float4 sv[8];
            #pragma unroll
            for (int i = 0; i < 8; i++) sv[i] = *(const float4*)&s_t[(g * 8 + i) * 128 + k];
            #pragma unroll
            for (int kk = 0; kk < 4; kk++) {
                float w = W1[(size_t)(k + kk) * 128 + c];
                #pragma unroll
                for (int i = 0; i < 8; i++) acc[i] = fmaf((&sv[i].x)[kk], w, acc[i]);
            }
        }
        #pragma unroll
        for (int i = 0; i < 8; i++) h_t[(g * 8 + i) * 128 + c] = silu_f(acc[i]);
    }
    __syncthreads();
    {
        float acc[8][3];
        #pragma unroll
        for (int q = 0; q < 3; q++) {
            float bb = b2[c + 128 * q];
            #pragma unroll
            for (int i = 0; i < 8; i++) acc[i][q] = bb;
        }
        for (int k = 0; k < 128; k += 4) {
            float4 hv[8];
            #pragma unroll
            for (int i = 0; i < 8; i++) hv[i] = *(const float4*)&h_t[(g * 8 + i) * 128 + k];
            #pragma unroll
            for (int kk = 0; kk < 4; kk++) {
                float w0 = W2[(size_t)(k + kk) * 384 + c];
                float w1 = W2[(size_t)(k + kk) * 384 + c + 128];
                float w2 = W2[(size_t)(k + kk) * 384 + c + 256];
                #pragma unroll
                for (int i = 0; i < 8; i++) {
                    float a = (&hv[i].x)[kk];
                    acc[i][0] = fmaf(a, w0, acc[i][0]);
                    acc[i][1] = fmaf(a, w1, acc[i][1]);
                    acc[i][2] = fmaf(a, w2, acc[i][2]);
                }
            }
        }
        #pragma unroll
        for (int i = 0; i < 8; i++)
            #pragma unroll
            for (int q = 0; q < 3; q++)
                mf[(nb + g * 8 + i) * 384 + c + 128 * q] = acc[i][q];
    }
}

// ---------------------------------------------------------------- CSR edge kernel
// Round-10's proven 4-edge-chunk loop (unguarded prefetch, guarded consume)
// + vNew epilogue (folds v + dv*invsqrtH; saves k_updmf a full v read).
__global__ __launch_bounds__(256, 1) void k_edge11(const int* __restrict__ ei,
                                                   const float* __restrict__ evec,
                                                   const float* __restrict__ mf,
                                                   const float* __restrict__ v,
                                                   const float* __restrict__ Wr,
                                                   const float* __restrict__ br,
                                                   const int* __restrict__ offs,
                                                   const int* __restrict__ perm,
                                                   const float2* __restrict__ curc2,
                                                   float* __restrict__ s,
                                                   float* __restrict__ vNew,
                                                   int nN) {
    __shared__ float wrl[8064];
    for (int t = threadIdx.x; t < 8064; t += 256)
        wrl[t] = (t < 7680) ? Wr[t] : br[t - 7680];
    __syncthreads();

    const int lane = threadIdx.x & 63;
    const int wvi = __builtin_amdgcn_readfirstlane(threadIdx.x >> 6);
    const int nbase = blockIdx.x * 16 + wvi * 4;
    const float inv_sqrt3 = 0.57735026918962576451f;
    const float inv_sqrtH = 0.08838834764831845f;

    float brv[6];
    #pragma unroll
    for (int q = 0; q < 6; ++q) brv[q] = wrl[7680 + q * 64 + lane];

    for (int j = 0; j < 4; ++j) {
        const int n = nbase + j;
        if (n >= nN) break;
        const int beg = offs[n], end = offs[n + 1];

        float sa0 = 0.f, sa1 = 0.f;
        float dv00 = 0.f, dv10 = 0.f, dv20 = 0.f;
        float dv01 = 0.f, dv11 = 0.f, dv21 = 0.f;

        for (int i = beg; i < end; i += 4) {
            const int ne = end - i;   // wave-uniform
            int src[4];
            float ux[4], uy[4], uz[4], cur[4], prev[4], c2v[4];
            #pragma unroll
            for (int t = 0; t < 4; ++t) {
                int e = perm[i + t];
                float2 cc = curc2[i + t];
                cur[t] = cc.x; c2v[t] = cc.y; prev[t] = 0.f;
                src[t] = ei[e];
                float ex = evec[3 * e], ey = evec[3 * e + 1], ez = evec[3 * e + 2];
                float rn = 1.0f / sqrtf(ex * ex + ey * ey + ez * ez);
                ux[t] = ex * rn; uy[t] = ey * rn; uz[t] = ez * rn;
            }
            float gm[4][6], gv[4][6];
            #pragma unroll
            for (int t = 0; t < 4; ++t) {
                const float* mfr = mf + (size_t)src[t] * 384 + lane;
                const float* vr  = v  + (size_t)src[t] * 384 + lane;
                #pragma unroll
                for (int q = 0; q < 6; ++q) { gm[t][q] = mfr[q * 64]; gv[t][q] = vr[q * 64]; }
            }
            float wf[4][6];
            #pragma unroll
            for (int t = 0; t < 4; ++t)
                #pragma unroll
                for (int q = 0; q < 6; ++q) wf[t][q] = brv[q];
            for (int rr = 0; rr < 20; ++rr) {
                float w6[6];
                #pragma unroll
                for (int q = 0; q < 6; ++q) w6[q] = wrl[rr * 384 + q * 64 + lane];
                #pragma unroll
                for (int t = 0; t < 4; ++t) {
                    float c = cur[t];
                    #pragma unroll
                    for (int q = 0; q < 6; ++q) wf[t][q] = fmaf(c, w6[q], wf[t][q]);
                    float nx = fmaf(c2v[t], c, -prev[t]);
                    prev[t] = c; cur[t] = nx;
                }
            }
            #pragma unroll
            for (int t = 0; t < 4; ++t) {
                if (t < ne) {
                    sa0 = fmaf(wf[t][0], gm[t][0], sa0);
                    sa1 = fmaf(wf[t][1], gm[t][1], sa1);
                    float a0 = wf[t][2] * gm[t][2] * inv_sqrt3;
                    float a1 = wf[t][3] * gm[t][3] * inv_sqrt3;
                    float b0 = wf[t][4] * gm[t][4];
                    float b1 = wf[t][5] * gm[t][5];
                    dv00 = fmaf(gv[t][0], a0, fmaf(ux[t], b0, dv00));
                    dv10 = fmaf(gv[t][2], a0, fmaf(uy[t], b0, dv10));
                    dv20 = fmaf(gv[t][4], a0, fmaf(uz[t], b0, dv20));
                    dv01 = fmaf(gv[t][1], a1, fmaf(ux[t], b1, dv01));
                    dv11 = fmaf(gv[t][3], a1, fmaf(uy[t], b1, dv11));
                    dv21 = fmaf(gv[t][5], a1, fmaf(uz[t], b1, dv21));
                }
            }
        }

        float* sp = s + (size_t)n * 128;
        sp[lane] += sa0;
        sp[64 + lane] += sa1;
        const float* vo = v + (size_t)n * 384;
        float* dp = vNew + (size_t)n * 384;
        dp[lane]       = fmaf(dv00, inv_sqrtH, vo[lane]);
        dp[64 + lane]  = fmaf(dv01, inv_sqrtH, vo[64 + lane]);
        dp[128 + lane] = fmaf(dv10, inv_sqrtH, vo[128 + lane]);
        dp[192 + lane] = fmaf(dv11, inv_sqrtH, vo[192 + lane]);
        dp[256 + lane] = fmaf(dv20, inv_sqrtH, vo[256 + lane]);
        dp[320 + lane] = fmaf(dv21, inv_sqrtH, vo[320 + lane]);
    }
}

// ---------------------------------------------------------------- fused node update + next-layer mf
__global__ __launch_bounds__(256, 3) void k_updmf(float* __restrict__ s,
                                                  float* __restrict__ v,
                                                  const float* __restrict__ vNew,
                                                  const float* __restrict__ Wv,
                                                  const float* __restrict__ W1,
                                                  const float* __restrict__ b1,
                                                  const float* __restrict__ W2,
                                                  const float* __restrict__ b2,
                                                  const float* __restrict__ W1m,
                                                  const float* __restrict__ b1m,
                                                  const float* __restrict__ W2m,
                                                  const float* __restrict__ b2m,
                                                  float* __restrict__ mf) {
    __shared__ float sv[16 * 128];
    __shared__ float vn[16 * 384];
    __shared__ float vnl[16 * 128];
    __shared__ float u1[16 * 128];
    const int tid = threadIdx.x;
    const size_t nb = (size_t)blockIdx.x * 16;
    const float inv_sqrtH = 0.08838834764831845f;
    const float inv_sqrt2 = 0.70710678118654752440f;

    {
        const float4* s4 = (const float4*)(s + nb * 128);
        ((float4*)sv)[tid] = s4[tid];
        ((float4*)sv)[tid + 256] = s4[tid + 256];
        const float4* e4 = (const float4*)(vNew + nb * 384);
        #pragma unroll
        for (int t = 0; t < 6; ++t)
            ((float4*)vn)[tid + 256 * t] = e4[tid + 256 * t];
    }
    __syncthreads();
    const int c0 = tid & 63;
    const int ty = tid >> 6;
    float acc[4][3][4];
    {
        #pragma unroll
        for (int i = 0; i < 4; i++)
            #pragma unroll
            for (int d = 0; d < 3; d++)
                #pragma unroll
                for (int cc = 0; cc < 4; cc++) acc[i][d][cc] = 0.f;
        for (int k = 0; k < 128; k += 4) {
            float4 av[4][3];
            #pragma unroll
            for (int i = 0; i < 4; i++)
                #pragma unroll
                for (int d = 0; d < 3; d++)
                    av[i][d] = *(const float4*)&vn[(ty * 4 + i) * 384 + d * 128 + k];
            #pragma unroll
            for (int kk = 0; kk < 4; kk++) {
                float wc[4];
                #pragma unroll
                for (int cc = 0; cc < 4; cc++) wc[cc] = Wv[(size_t)(k + kk) * 256 + c0 + 64 * cc];
                #pragma unroll
                for (int i = 0; i < 4; i++)
                    #pragma unroll
                    for (int d = 0; d < 3; d++) {
                        float a = (&av[i][d].x)[kk];
                        #pragma unroll
                        for (int cc = 0; cc < 4; cc++)
                            acc[i][d][cc] = fmaf(a, wc[cc], acc[i][d][cc]);
                    }
            }
        }
    }
    float vdot[4][2];
    {
        #pragma unroll
        for (int i = 0; i < 4; i++)
            #pragma unroll
            for (int hh = 0; hh < 2; hh++) {
                float d0 = acc[i][0][hh] * acc[i][0][hh + 2] + acc[i][1][hh] * acc[i][1][hh + 2] +
                           acc[i][2][hh] * acc[i][2][hh + 2];
                vdot[i][hh] = d0 * inv_sqrtH;
                float n2 = acc[i][0][hh + 2] * acc[i][0][hh + 2] +
                           acc[i][1][hh + 2] * acc[i][1][hh + 2] +
                           acc[i][2][hh + 2] * acc[i][2][hh + 2];
                vnl[(ty * 4 + i) * 128 + c0 + 64 * hh] = sqrtf(n2 + 1e-12f);
            }
    }
    __syncthreads();
    {
        float a3[4][2];
        float bb0 = b1[c0], bb1 = b1[c0 + 64];
        #pragma unroll
        for (int i = 0; i < 4; i++) { a3[i][0] = bb0; a3[i][1] = bb1; }
        for (int k = 0; k < 128; k += 4) {
            float4 f[4];
            #pragma unroll
            for (int i = 0; i < 4; i++) f[i] = *(const float4*)&sv[(ty * 4 + i) * 128 + k];
            #pragma unroll
            for (int kk = 0; kk < 4; kk++) {
                float w0 = W1[(size_t)(k + kk) * 128 + c0];
                float w1 = W1[(size_t)(k + kk) * 128 + c0 + 64];
                #pragma unroll
                for (int i = 0; i < 4; i++) {
                    float a = (&f[i].x)[kk];
                    a3[i][0] = fmaf(a, w0, a3[i][0]);
                    a3[i][1] = fmaf(a, w1, a3[i][1]);
                }
            }
        }
        for (int k = 0; k < 128; k += 4) {
            float4 f[4];
            #pragma unroll
            for (int i = 0; i < 4; i++) f[i] = *(const float4*)&vnl[(ty * 4 + i) * 128 + k];
            #pragma unroll
            for (int kk = 0; kk < 4; kk++) {
                float w0 = W1[(size_t)(k + kk + 128) * 128 + c0];
                float w1 = W1[(size_t)(k + kk + 128) * 128 + c0 + 64];
                #pragma unroll
                for (int i = 0; i < 4; i++) {
                    float a = (&f[i].x)[kk];
                    a3[i][0] = fmaf(a, w0, a3[i][0]);
                    a3[i][1] = fmaf(a, w1, a3[i][1]);
                }
            }
        }
        #pragma unroll
        for (int i = 0; i < 4; i++) {
            u1[(ty * 4 + i) * 128 + c0] = silu_f(a3[i][0]);
            u1[(ty * 4 + i) * 128 + c0 + 64] = silu_f(a3[i][1]);
        }
    }
    __syncthreads();
    {
        float a4[4][6];
        #pragma unroll
        for (int q = 0; q < 6; q++) {
            float bb = b2[c0 + 64 * q];
            #pragma unroll
            for (int i = 0; i < 4; i++) a4[i][q] = bb;
        }
        for (int k = 0; k < 128; k += 4) {
            float4 uu[4];
            #pragma unroll
            for (int i = 0; i < 4; i++) uu[i] = *(const float4*)&u1[(ty * 4 + i) * 128 + k];
            #pragma unroll
            for (int kk = 0; kk < 4; kk++) {
                float w[6];
                #pragma unroll
                for (int q = 0; q < 6; q++) w[q] = W2[(size_t)(k + kk) * 384 + c0 + 64 * q];
                #pragma unroll
                for (int i = 0; i < 4; i++) {
                    float a = (&uu[i].x)[kk];
                    #pragma unroll
                    for (int q = 0; q < 6; q++) a4[i][q] = fmaf(a, w[q], a4[i][q]);
                }
            }
        }
        __syncthreads();   // all u1/sv reads done before sv overwrite
        #pragma unroll
        for (int i = 0; i < 4; i++) {
            int node = ty * 4 + i;
            size_t nr = nb + node;
            #pragma unroll
            for (int hh = 0; hh < 2; ++hh) {
                int h = c0 + 64 * hh;
                float a_ss = a4[i][hh], a_sv = a4[i][2 + hh], a_v = a4[i][4 + hh];
                float snew = sv[node * 128 + h] + (vdot[i][hh] * a_sv + a_ss) * inv_sqrt2;
                s[nr * 128 + h] = snew;
                sv[node * 128 + h] = snew;
                #pragma unroll
                for (int d = 0; d < 3; ++d)
                    v[nr * 384 + d * 128 + h] =
                        vn[node * 384 + d * 128 + h] + acc[i][d][hh] * a_v;
            }
        }
    }
    __syncthreads();
    // -------- fused mf(l+1)
    const int c = tid & 127;
    const int g = tid >> 7;
    {
        float am[8];
        float bb = b1m[c];
        #pragma unroll
        for (int i = 0; i < 8; i++) am[i] = bb;
        for (int k = 0; k < 128; k += 4) {
            float4 svv[8];
            #pragma unroll
            for (int i = 0; i < 8; i++) svv[i] = *(const float4*)&sv[(g * 8 + i) * 128 + k];
            #pragma unroll
            for (int kk = 0; kk < 4; kk++) {
                float w = W1m[(size_t)(k + kk) * 128 + c];
                #pragma unroll
                for (int i = 0; i < 8; i++) am[i] = fmaf((&svv[i].x)[kk], w, am[i]);
            }
        }
        #pragma unroll
        for (int i = 0; i < 8; i++) u1[(g * 8 + i) * 128 + c] = silu_f(am[i]);
    }
    __syncthreads();
    {
        float am[8][3];
        #pragma unroll
        for (int q = 0; q < 3; q++) {
            float bb = b2m[c + 128 * q];
            #pragma unroll
            for (int i = 0; i < 8; i++) am[i][q] = bb;
        }
        for (int k = 0; k < 128; k += 4) {
            float4 hv[8];
            #pragma unroll
            for (int i = 0; i < 8; i++) hv[i] = *(const float4*)&u1[(g * 8 + i) * 128 + k];
            #pragma unroll
            for (int kk = 0; kk < 4; kk++) {
                float w0 = W2m[(size_t)(k + kk) * 384 + c];
                float w1 = W2m[(size_t)(k + kk) * 384 + c + 128];
                float w2 = W2m[(size_t)(k + kk) * 384 + c + 256];
                #pragma unroll
                for (int i = 0; i < 8; i++) {
                    float a = (&hv[i].x)[kk];
                    am[i][0] = fmaf(a, w0, am[i][0]);
                    am[i][1] = fmaf(a, w1, am[i][1]);
                    am[i][2] = fmaf(a, w2, am[i][2]);
                }
            }
        }
        #pragma unroll
        for (int i = 0; i < 8; i++)
            #pragma unroll
            for (int q = 0; q < 3; q++)
                mf[(nb + g * 8 + i) * 384 + c + 128 * q] = am[i][q];
    }
}

// ---------------------------------------------------------------- fused final update + output head
__global__ __launch_bounds__(256, 3) void k_updout(const float* __restrict__ s,
                                                   const float* __restrict__ vNew,
                                                   const float* __restrict__ Wv,
                                                   const float* __restrict__ W1,
                                                   const float* __restrict__ b1,
                                                   const float* __restrict__ W2,
                                                   const float* __restrict__ b2,
                                                   const float* __restrict__ ow1,
                                                   const float* __restrict__ ob1,
                                                   const float* __restrict__ ow2,
                                                   const float* __restrict__ ob2,
                                                   float* __restrict__ out, int nNodes) {
    __shared__ float sv[16 * 128];
    __shared__ float vn[16 * 384];
    __shared__ float vnl[16 * 128];
    __shared__ float u1[16 * 128];
    __shared__ float red[4];
    const int tid = threadIdx.x;
    const size_t nb = (size_t)blockIdx.x * 16;
    const float inv_sqrtH = 0.08838834764831845f;
    const float inv_sqrt2 = 0.70710678118654752440f;

    {
        const float4* s4 = (const float4*)(s + nb * 128);
        ((float4*)sv)[tid] = s4[tid];
        ((float4*)sv)[tid + 256] = s4[tid + 256];
        const float4* e4 = (const float4*)(vNew + nb * 384);
        #pragma unroll
        for (int t = 0; t < 6; ++t)
            ((float4*)vn)[tid + 256 * t] = e4[tid + 256 * t];
    }
    __syncthreads();
    const int c0 = tid & 63;
    const int ty = tid >> 6;
    float acc[4][3][4];
    {
        #pragma unroll
        for (int i = 0; i < 4; i++)
            #pragma unroll
            for (int d = 0; d < 3; d++)
                #pragma unroll
                for (int cc = 0; cc < 4; cc++) acc[i][d][cc] = 0.f;
        for (int k = 0; k < 128; k += 4) {
            float4 av[4][3];
            #pragma unroll
            for (int i = 0; i < 4; i++)
                #pragma unroll
                for (int d = 0; d < 3; d++)
                    av[i][d] = *(const float4*)&vn[(ty * 4 + i) * 384 + d * 128 + k];
            #pragma unroll
            for (int kk = 0; kk < 4; kk++) {
                float wc[4];
                #pragma unroll
                for (int cc = 0; cc < 4; cc++) wc[cc] = Wv[(size_t)(k + kk) * 256 + c0 + 64 * cc];
                #pragma unroll
                for (int i = 0; i < 4; i++)
                    #pragma unroll
                    for (int d = 0; d < 3; d++) {
                        float a = (&av[i][d].x)[kk];
                        #pragma unroll
                        for (int cc = 0; cc < 4; cc++)
                            acc[i][d][cc] = fmaf(a, wc[cc], acc[i][d][cc]);
                    }
            }
        }
    }
    float vdot[4][2];
    {
        #pragma unroll
        for (int i = 0; i < 4; i++)
            #pragma unroll
            for (int hh = 0; hh < 2; hh++) {
                float d0 = acc[i][0][hh] * acc[i][0][hh + 2] + acc[i][1][hh] * acc[i][1][hh + 2] +
                           acc[i][2][hh] * acc[i][2][hh + 2];
                vdot[i][hh] = d0 * inv_sqrtH;
                float n2 = acc[i][0][hh + 2] * acc[i][0][hh + 2] +
                           acc[i][1][hh + 2] * acc[i][1][hh + 2] +
                           acc[i][2][hh + 2] * acc[i][2][hh + 2];
                vnl[(ty * 4 + i) * 128 + c0 + 64 * hh] = sqrtf(n2 + 1e-12f);
            }
    }
    __syncthreads();
    {
        float a3[4][2];
        float bb0 = b1[c0], bb1 = b1[c0 + 64];
        #pragma unroll
        for (int i = 0; i < 4; i++) { a3[i][0] = bb0; a3[i][1] = bb1; }
        for (int k = 0; k < 128; k += 4) {
            float4 f[4];
            #pragma unroll
            for (int i = 0; i < 4; i++) f[i] = *(const float4*)&sv[(ty * 4 + i) * 128 + k];
            #pragma unroll
            for (int kk = 0; kk < 4; kk++) {
                float w0 = W1[(size_t)(k + kk) * 128 + c0];
                float w1 = W1[(size_t)(k + kk) * 128 + c0 + 64];
                #pragma unroll
                for (int i = 0; i < 4; i++) {
                    float a = (&f[i].x)[kk];
                    a3[i][0] = fmaf(a, w0, a3[i][0]);
                    a3[i][1] = fmaf(a, w1, a3[i][1]);
                }
            }
        }
        for (int k = 0; k < 128; k += 4) {
            float4 f[4];
            #pragma unroll
            for (int i = 0; i < 4; i++) f[i] = *(const float4*)&vnl[(ty * 4 + i) * 128 + k];
            #pragma unroll
            for (int kk = 0; kk < 4; kk++) {
                float w0 = W1[(size_t)(k + kk + 128) * 128 + c0];
                float w1 = W1[(size_t)(k + kk + 128) * 128 + c0 + 64];
                #pragma unroll
                for (int i = 0; i < 4; i++) {
                    float a = (&f[i].x)[kk];
                    a3[i][0] = fmaf(a, w0, a3[i][0]);
                    a3[i][1] = fmaf(a, w1, a3[i][1]);
                }
            }
        }
        #pragma unroll
        for (int i = 0; i < 4; i++) {
            u1[(ty * 4 + i) * 128 + c0] = silu_f(a3[i][0]);
            u1[(ty * 4 + i) * 128 + c0 + 64] = silu_f(a3[i][1]);
        }
    }
    __syncthreads();
    {
        float a4[4][6];
        #pragma unroll
        for (int q = 0; q < 6; q++) {
            float bb = b2[c0 + 64 * q];
            #pragma unroll
            for (int i = 0; i < 4; i++) a4[i][q] = bb;
        }
        for (int k = 0; k < 128; k += 4) {
            float4 uu[4];
            #pragma unroll
            for (int i = 0; i < 4; i++) uu[i] = *(const float4*)&u1[(ty * 4 + i) * 128 + k];
            #pragma unroll
            for (int kk = 0; kk < 4; kk++) {
                float w[6];
                #pragma unroll
                for (int q = 0; q < 6; q++) w[q] = W2[(size_t)(k + kk) * 384 + c0 + 64 * q];
                #pragma unroll
                for (int i = 0; i < 4; i++) {
                    float a = (&uu[i].x)[kk];
                    #pragma unroll
                    for (int q = 0; q < 6; q++) a4[i][q] = fmaf(a, w[q], a4[i][q]);
                }
            }
        }
        __syncthreads();
        #pragma unroll
        for (int i = 0; i < 4; i++) {
            int node = ty * 4 + i;
            #pragma unroll
            for (int hh = 0; hh < 2; ++hh) {
                int h = c0 + 64 * hh;
                sv[node * 128 + h] = sv[node * 128 + h] +
                                     (vdot[i][hh] * a4[i][2 + hh] + a4[i][hh]) * inv_sqrt2;
            }
        }
    }
    __syncthreads();
    {
        float ao[4];
        float bb = ob1[c0];
        #pragma unroll
        for (int i = 0; i < 4; i++) ao[i] = bb;
        for (int k = 0; k < 128; k += 4) {
            float4 f[4];
            #pragma unroll
            for (int i = 0; i < 4; i++) f[i] = *(const float4*)&sv[(ty * 4 + i) * 128 + k];
            #pragma unroll
            for (int kk = 0; kk < 4; kk++) {
                float w = ow1[(size_t)(k + kk) * 64 + c0];
                #pragma unroll
                for (int i = 0; i < 4; i++) ao[i] = fmaf((&f[i].x)[kk], w, ao[i]);
            }
        }
        float w2 = ow2[c0];
        float p = 0.f;
        #pragma unroll
        for (int i = 0; i < 4; i++) p += silu_f(ao[i]) * w2;
        #pragma unroll
        for (int off = 32; off > 0; off >>= 1) p += __shfl_down(p, off, 64);
        if (c0 == 0) red[ty] = p;
        __syncthreads();
        if (tid == 0) {
            float val = (red[0] + red[1] + red[2] + red[3]) * (1.0f / (float)nNodes);
            if (blockIdx.x == 0) val += ob2[0];
            atomicAdd(out, val);
        }
    }
}

// ----------------------------------------------------------------
extern "C" void kernel_launch(void* const* d_in, const int* in_sizes, int n_in,
                              void* d_out, int out_size, void* d_ws, size_t ws_size,
                              hipStream_t stream) {
    const int*   z     = (const int*)d_in[0];
    const int*   ei    = (const int*)d_in[1];
    const float* edist = (const float*)d_in[2];
    const float* evec  = (const float*)d_in[3];
    const float* emb   = (const float*)d_in[4];
    const float* mw1   = (const float*)d_in[5];
    const float* mb1   = (const float*)d_in[6];
    const float* mw2   = (const float*)d_in[7];
    const float* mb2   = (const float*)d_in[8];
    const float* rw    = (const float*)d_in[9];
    const float* rbb   = (const float*)d_in[10];
    const float* uvw   = (const float*)d_in[11];
    const float* uw1   = (const float*)d_in[12];
    const float* ub1   = (const float*)d_in[13];
    const float* uw2   = (const float*)d_in[14];
    const float* ub2   = (const float*)d_in[15];
    const float* ow1   = (const float*)d_in[16];
    const float* ob1   = (const float*)d_in[17];
    const float* ow2   = (const float*)d_in[18];
    const float* ob2   = (const float*)d_in[19];

    const int N = in_sizes[0];
    const int E = in_sizes[2];
    const int Ep = E + 8;

    const size_t need = ((size_t)N * 1280 + (N + 1) + Ep) * 4 + (size_t)Ep * 8;
    hipMemsetAsync(d_out, 0, out_size * sizeof(float), stream);
    if (ws_size < need) return;

    float* ws = (float*)d_ws;
    float*  s     = ws;
    float*  v     = s + (size_t)N * 128;
    float*  mf    = v + (size_t)N * 384;
    float*  vNew  = mf + (size_t)N * 384;
    int*    offs  = (int*)(vNew + (size_t)N * 384);
    int*    perm  = offs + (N + 1);
    float2* curc2 = (float2*)(perm + Ep);
    int*    cnt   = (int*)curc2;     // build-time aliases
    int*    cur   = cnt + N;
    int*    btot  = cur + N;
    int*    btot2 = btot + 64;

    hipMemsetAsync(v, 0, (size_t)N * 384 * sizeof(float), stream);
    hipMemsetAsync(cnt, 0, (size_t)2 * N * sizeof(int), stream);

    const int nbScan = (N + 1023) / 1024;
    k_count<<<(E + 255) / 256, 256, 0, stream>>>(ei, cnt, E);
    k_scan_blk<<<nbScan, 1024, 0, stream>>>(cnt, offs, btot, N);
    k_scan_top<<<1, 64, 0, stream>>>(btot, btot2, nbScan, offs + N);
    k_scan_add<<<(N + 255) / 256, 256, 0, stream>>>(offs, btot2, N);
    k_fill<<<(E + 255) / 256, 256, 0, stream>>>(ei, offs, cur, perm, E);
    k_prep<<<(Ep + 255) / 256, 256, 0, stream>>>(edist, perm, curc2, E, Ep);

    k_initmf<<<N / 16, 256, 0, stream>>>(z, emb, s, mw1, mb1, mw2, mb2, mf);

    for (int l = 0; l < 3; ++l) {
        k_edge11<<<(N + 15) / 16, 256, 0, stream>>>(ei, evec, mf, v,
                                                    rw + (size_t)l * 7680, rbb + l * 384,
                                                    offs, perm, curc2, s, vNew, N);
        if (l < 2) {
            k_updmf<<<N / 16, 256, 0, stream>>>(s, v, vNew, uvw + (size_t)l * 32768,
                                                uw1 + (size_t)l * 32768, ub1 + l * 128,
                                                uw2 + (size_t)l * 49152, ub2 + l * 384,
                                                mw1 + (size_t)(l + 1) * 16384, mb1 + (l + 1) * 128,
                                                mw2 + (size_t)(l + 1) * 49152, mb2 + (l + 1) * 384,
                                                mf);
        } else {
            k_updout<<<N / 16, 256, 0, stream>>>(s, vNew, uvw + (size_t)l * 32768,
                                                 uw1 + (size_t)l * 32768, ub1 + l * 128,
                                                 uw2 + (size_t)l * 49152, ub2 + l * 384,
                                                 ow1, ob1, ow2, ob2, (float*)d_out, N);
        }
    }
}